// Round 1
// baseline (457.727 us; speedup 1.0000x reference)
//
#include <hip/hip_runtime.h>

#define DDIM 1024
#define HHEADS 16
#define FFN_DIM 4096
#define BB 4
#define SS 1024
#define MTOK 4096  // B*S

typedef __bf16 bf16x8 __attribute__((ext_vector_type(8)));
typedef float f32x4 __attribute__((ext_vector_type(4)));
typedef unsigned short ushort4v __attribute__((ext_vector_type(4)));
typedef unsigned short ushort8v __attribute__((ext_vector_type(8)));

__device__ __forceinline__ unsigned short f2bf(float f) {
    union { float f; unsigned u; } x;
    x.f = f;
    unsigned r = x.u + 0x7FFFu + ((x.u >> 16) & 1u);
    return (unsigned short)(r >> 16);
}

// async global->LDS, 16B per lane. LDS dest = wave-uniform base + lane*16.
__device__ __forceinline__ void gload_lds16(const void* g, void* l) {
    __builtin_amdgcn_global_load_lds(
        (__attribute__((address_space(1))) unsigned int*)(unsigned long long)(g),
        (__attribute__((address_space(3))) unsigned int*)(l), 16, 0, 0);
}

// ---------------------------------------------------------------------------
// f32 -> bf16 conversion, 4 elems/thread
// ---------------------------------------------------------------------------
__global__ __launch_bounds__(256) void cvt_bf16(const float* __restrict__ in,
                                                unsigned short* __restrict__ out, int n4) {
    int i = blockIdx.x * 256 + threadIdx.x;
    if (i < n4) {
        float4 v = ((const float4*)in)[i];
        ushort4v u = {f2bf(v.x), f2bf(v.y), f2bf(v.z), f2bf(v.w)};
        ((ushort4v*)out)[i] = u;
    }
}

// ---------------------------------------------------------------------------
// C[M,N] = A[M,K] @ B[N,K]^T + bias  (bf16 in, f32 acc)
// EPI: 0 = f32 out, 1 = bf16 out, 2 = relu -> bf16 out
// 128x128 tile, BK=32, 256 threads (4 waves, 2x2 of 64x64), 16x16x32 MFMA
// ---------------------------------------------------------------------------
template <int EPI>
__global__ __launch_bounds__(256) void gemm_bt(const unsigned short* __restrict__ A,
                                               const unsigned short* __restrict__ B,
                                               const float* __restrict__ bias,
                                               void* __restrict__ Cout,
                                               int M, int N, int K) {
    __shared__ unsigned short Asm[128 * 32];
    __shared__ unsigned short Bsm[128 * 32];
    const int tid = threadIdx.x;
    const int wid = tid >> 6, lane = tid & 63;
    const int m0 = blockIdx.y * 128, n0 = blockIdx.x * 128;
    const int lr = lane & 15, lk = (lane >> 4) * 8;
    const int wr = (wid >> 1) * 64, wc = (wid & 1) * 64;

    f32x4 acc[4][4];
#pragma unroll
    for (int i = 0; i < 4; i++)
#pragma unroll
        for (int j = 0; j < 4; j++) acc[i][j] = (f32x4){0.f, 0.f, 0.f, 0.f};

    const unsigned short* Ag = A + (size_t)m0 * K;
    const unsigned short* Bg = B + (size_t)n0 * K;

    for (int k0 = 0; k0 < K; k0 += 32) {
        // stage 8KB per operand: rows of 32 bf16 = 64B; pass p covers 4KB
#pragma unroll
        for (int p = 0; p < 2; ++p) {
            int idx = p * 4096 + wid * 1024 + lane * 16;  // byte within tile buf
            int row = idx >> 6, colb = idx & 63;
            gload_lds16(Ag + (size_t)row * K + k0 + (colb >> 1),
                        (char*)Asm + p * 4096 + wid * 1024);
            gload_lds16(Bg + (size_t)row * K + k0 + (colb >> 1),
                        (char*)Bsm + p * 4096 + wid * 1024);
        }
        __syncthreads();
        bf16x8 af[4], bf[4];
#pragma unroll
        for (int m = 0; m < 4; m++) af[m] = *(const bf16x8*)&Asm[(wr + m * 16 + lr) * 32 + lk];
#pragma unroll
        for (int n = 0; n < 4; n++) bf[n] = *(const bf16x8*)&Bsm[(wc + n * 16 + lr) * 32 + lk];
#pragma unroll
        for (int m = 0; m < 4; m++)
#pragma unroll
            for (int n = 0; n < 4; n++)
                acc[m][n] = __builtin_amdgcn_mfma_f32_16x16x32_bf16(af[m], bf[n], acc[m][n], 0, 0, 0);
        __syncthreads();
    }

    // epilogue: C/D layout col = lane&15, row = (lane>>4)*4 + reg
    float bv[4];
#pragma unroll
    for (int n = 0; n < 4; n++) bv[n] = bias[n0 + wc + n * 16 + lr];
    const int r0 = (lane >> 4) * 4;
#pragma unroll
    for (int m = 0; m < 4; m++) {
#pragma unroll
        for (int n = 0; n < 4; n++) {
            int col = n0 + wc + n * 16 + lr;
#pragma unroll
            for (int r = 0; r < 4; r++) {
                int row = m0 + wr + m * 16 + r0 + r;
                float v = acc[m][n][r] + bv[n];
                if (EPI == 0) {
                    ((float*)Cout)[(size_t)row * N + col] = v;
                } else if (EPI == 1) {
                    ((unsigned short*)Cout)[(size_t)row * N + col] = f2bf(v);
                } else {
                    ((unsigned short*)Cout)[(size_t)row * N + col] = f2bf(fmaxf(v, 0.f));
                }
            }
        }
    }
}

// ---------------------------------------------------------------------------
// Flash attention: one block per (b,h,64-row q-tile). 4 waves, 16 q-rows each.
// qkv: [B*S, 3072] bf16 (q cols 0..1023, k 1024..2047, v 2048..3071)
// ctx: [B*S, 1024] bf16 out
// ---------------------------------------------------------------------------
__global__ __launch_bounds__(256) void attn_fused(const unsigned short* __restrict__ qkv,
                                                  const int* __restrict__ mask,
                                                  unsigned short* __restrict__ ctx) {
    __shared__ unsigned short Ksm[64 * 64];
    __shared__ unsigned short Vt[64 * 64];
    __shared__ unsigned short Psm[4][16 * 64];
    __shared__ float maskadd[64];
    const int tid = threadIdx.x, wid = tid >> 6, lane = tid & 63;
    const int bh = blockIdx.y, b = bh >> 4, h = bh & 15;
    const int q0 = blockIdx.x * 64;
    const int lr = lane & 15, lk = (lane >> 4) * 8;
    const size_t base = (size_t)b * SS * 3072 + h * 64;

    bf16x8 qf[2];
    {
        const unsigned short* qp = qkv + base + (size_t)(q0 + wid * 16 + lr) * 3072;
        qf[0] = *(const bf16x8*)(qp + lk);
        qf[1] = *(const bf16x8*)(qp + 32 + lk);
    }
    float m_run[4] = {-3e38f, -3e38f, -3e38f, -3e38f};
    float l_run[4] = {0.f, 0.f, 0.f, 0.f};
    f32x4 oacc[4];
#pragma unroll
    for (int i = 0; i < 4; i++) oacc[i] = (f32x4){0.f, 0.f, 0.f, 0.f};

    for (int kt = 0; kt < SS / 64; ++kt) {
        const unsigned short* Kg = qkv + base + (size_t)(kt * 64) * 3072 + 1024;
        const unsigned short* Vg = qkv + base + (size_t)(kt * 64) * 3072 + 2048;
        // stage K tile [64 keys][64 d] (rows of 128B) via global_load_lds
#pragma unroll
        for (int p = 0; p < 2; p++) {
            int idx = p * 4096 + wid * 1024 + lane * 16;
            int row = idx >> 7, colb = idx & 127;
            gload_lds16(Kg + (size_t)row * 3072 + (colb >> 1),
                        (char*)Ksm + p * 4096 + wid * 1024);
        }
        // stage V transposed: Vt[d][key]
        ushort8v vv[2];
        int vr[2], vc[2];
#pragma unroll
        for (int p = 0; p < 2; p++) {
            int idx = p * 4096 + tid * 16;
            vr[p] = idx >> 7;
            vc[p] = (idx & 127) >> 1;
            vv[p] = *(const ushort8v*)(Vg + (size_t)vr[p] * 3072 + vc[p]);
        }
        if (tid < 64) maskadd[tid] = mask[bh * SS + kt * 64 + tid] ? 0.f : -1e9f;
#pragma unroll
        for (int p = 0; p < 2; p++)
#pragma unroll
            for (int i = 0; i < 8; i++) Vt[(vc[p] + i) * 64 + vr[p]] = vv[p][i];
        __syncthreads();

        // scores: S = Q(16x64) @ K^T(64x64), per wave
        f32x4 sc[4];
#pragma unroll
        for (int nt = 0; nt < 4; nt++) {
            f32x4 a = (f32x4){0.f, 0.f, 0.f, 0.f};
            bf16x8 k0v = *(const bf16x8*)&Ksm[(nt * 16 + lr) * 64 + lk];
            bf16x8 k1v = *(const bf16x8*)&Ksm[(nt * 16 + lr) * 64 + 32 + lk];
            a = __builtin_amdgcn_mfma_f32_16x16x32_bf16(qf[0], k0v, a, 0, 0, 0);
            a = __builtin_amdgcn_mfma_f32_16x16x32_bf16(qf[1], k1v, a, 0, 0, 0);
            sc[nt] = a;
        }
        float mk[4];
#pragma unroll
        for (int nt = 0; nt < 4; nt++) mk[nt] = maskadd[nt * 16 + lr];
#pragma unroll
        for (int r = 0; r < 4; r++) {
            float v = -3e38f;
#pragma unroll
            for (int nt = 0; nt < 4; nt++) {
                float s = sc[nt][r] * 0.125f + mk[nt];
                sc[nt][r] = s;
                v = fmaxf(v, s);
            }
            v = fmaxf(v, __shfl_xor(v, 1));
            v = fmaxf(v, __shfl_xor(v, 2));
            v = fmaxf(v, __shfl_xor(v, 4));
            v = fmaxf(v, __shfl_xor(v, 8));
            float mnew = fmaxf(m_run[r], v);
            float alpha = __expf(m_run[r] - mnew);
            m_run[r] = mnew;
            float ls = 0.f;
#pragma unroll
            for (int nt = 0; nt < 4; nt++) {
                float pexp = __expf(sc[nt][r] - mnew);
                sc[nt][r] = pexp;
                ls += pexp;
            }
            ls += __shfl_xor(ls, 1);
            ls += __shfl_xor(ls, 2);
            ls += __shfl_xor(ls, 4);
            ls += __shfl_xor(ls, 8);
            l_run[r] = l_run[r] * alpha + ls;
#pragma unroll
            for (int dt = 0; dt < 4; dt++) oacc[dt][r] *= alpha;
        }
        // P -> bf16 -> per-wave LDS (redistribute to A-frag layout)
        const int prow = (lane >> 4) * 4;
#pragma unroll
        for (int nt = 0; nt < 4; nt++)
#pragma unroll
            for (int r = 0; r < 4; r++)
                Psm[wid][(prow + r) * 64 + nt * 16 + lr] = f2bf(sc[nt][r]);
        // O += P(16x64) @ V(64x64)
        bf16x8 pf0 = *(const bf16x8*)&Psm[wid][lr * 64 + lk];
        bf16x8 pf1 = *(const bf16x8*)&Psm[wid][lr * 64 + 32 + lk];
#pragma unroll
        for (int dt = 0; dt < 4; dt++) {
            bf16x8 v0 = *(const bf16x8*)&Vt[(dt * 16 + lr) * 64 + lk];
            bf16x8 v1 = *(const bf16x8*)&Vt[(dt * 16 + lr) * 64 + 32 + lk];
            oacc[dt] = __builtin_amdgcn_mfma_f32_16x16x32_bf16(pf0, v0, oacc[dt], 0, 0, 0);
            oacc[dt] = __builtin_amdgcn_mfma_f32_16x16x32_bf16(pf1, v1, oacc[dt], 0, 0, 0);
        }
        __syncthreads();
    }
#pragma unroll
    for (int dt = 0; dt < 4; dt++) {
#pragma unroll
        for (int r = 0; r < 4; r++) {
            float v = oacc[dt][r] / l_run[r];
            int row = q0 + wid * 16 + (lane >> 4) * 4 + r;
            ctx[(size_t)(b * SS + row) * DDIM + h * 64 + dt * 16 + lr] = f2bf(v);
        }
    }
}

// ---------------------------------------------------------------------------
// out = LayerNorm(a + b) * gamma + beta, row-wise over D=1024.
// Optionally also writes bf16 copy.
// ---------------------------------------------------------------------------
__global__ __launch_bounds__(256) void resid_ln(const float* __restrict__ a,
                                                const float* __restrict__ b,
                                                const float* __restrict__ gamma,
                                                const float* __restrict__ beta,
                                                float* __restrict__ of32,
                                                unsigned short* __restrict__ obf) {
    __shared__ float red[16];
    const int row = blockIdx.x, tid = threadIdx.x;
    const int wid = tid >> 6, lane = tid & 63;
    float4 av = ((const float4*)(a + (size_t)row * DDIM))[tid];
    float4 bv = ((const float4*)(b + (size_t)row * DDIM))[tid];
    float4 v;
    v.x = av.x + bv.x; v.y = av.y + bv.y; v.z = av.z + bv.z; v.w = av.w + bv.w;
    float s = v.x + v.y + v.z + v.w;
    float s2 = v.x * v.x + v.y * v.y + v.z * v.z + v.w * v.w;
#pragma unroll
    for (int off = 1; off < 64; off <<= 1) {
        s += __shfl_xor(s, off);
        s2 += __shfl_xor(s2, off);
    }
    if (lane == 0) { red[wid] = s; red[8 + wid] = s2; }
    __syncthreads();
    s = red[0] + red[1] + red[2] + red[3];
    s2 = red[8] + red[9] + red[10] + red[11];
    float mean = s * (1.f / 1024.f);
    float var = s2 * (1.f / 1024.f) - mean * mean;
    float rstd = rsqrtf(var + 1e-12f);
    float4 g = ((const float4*)gamma)[tid];
    float4 be = ((const float4*)beta)[tid];
    float4 o;
    o.x = g.x * (v.x - mean) * rstd + be.x;
    o.y = g.y * (v.y - mean) * rstd + be.y;
    o.z = g.z * (v.z - mean) * rstd + be.z;
    o.w = g.w * (v.w - mean) * rstd + be.w;
    if (of32) ((float4*)(of32 + (size_t)row * DDIM))[tid] = o;
    if (obf) {
        ushort4v u = {f2bf(o.x), f2bf(o.y), f2bf(o.z), f2bf(o.w)};
        ((ushort4v*)(obf + (size_t)row * DDIM))[tid] = u;
    }
}

// ---------------------------------------------------------------------------
extern "C" void kernel_launch(void* const* d_in, const int* in_sizes, int n_in,
                              void* d_out, int out_size, void* d_ws, size_t ws_size,
                              hipStream_t stream) {
    const float* x    = (const float*)d_in[0];
    const int*   mask = (const int*)d_in[1];
    const float* Wqkv = (const float*)d_in[2];
    const float* bqkv = (const float*)d_in[3];
    const float* Wo   = (const float*)d_in[4];
    const float* bo   = (const float*)d_in[5];
    const float* W1   = (const float*)d_in[6];
    const float* b1   = (const float*)d_in[7];
    const float* W2   = (const float*)d_in[8];
    const float* b2   = (const float*)d_in[9];
    const float* g1   = (const float*)d_in[10];
    const float* be1  = (const float*)d_in[11];
    const float* g2   = (const float*)d_in[12];
    const float* be2  = (const float*)d_in[13];
    float* out = (float*)d_out;

    // workspace layout (bytes); ff1 overlaps [xbf|qkvbf] (dead by FFN1),
    // ff2 overlaps attn_out (dead after LN1). Total 104 MB.
    char* ws = (char*)d_ws;
    unsigned short* xbf   = (unsigned short*)(ws + 0);                    // 8 MB
    unsigned short* qkvbf = (unsigned short*)(ws + (8ull << 20));         // 24 MB
    unsigned short* ff1   = (unsigned short*)(ws + 0);                    // 32 MB (overlap)
    unsigned short* ctx   = (unsigned short*)(ws + (32ull << 20));        // 8 MB
    unsigned short* wqkvb = (unsigned short*)(ws + (40ull << 20));        // 6 MB
    unsigned short* wob   = (unsigned short*)(ws + (46ull << 20));        // 2 MB
    unsigned short* w1b   = (unsigned short*)(ws + (48ull << 20));        // 8 MB
    unsigned short* w2b   = (unsigned short*)(ws + (56ull << 20));        // 8 MB
    float* attno          = (float*)(ws + (64ull << 20));                 // 16 MB
    float* ff2            = (float*)(ws + (64ull << 20));                 // (overlap)
    float* hf             = (float*)(ws + (80ull << 20));                 // 16 MB
    unsigned short* hbf   = (unsigned short*)(ws + (96ull << 20));        // 8 MB

    cvt_bf16<<<4096, 256, 0, stream>>>(x, xbf, 1048576);
    cvt_bf16<<<3072, 256, 0, stream>>>(Wqkv, wqkvb, 786432);
    cvt_bf16<<<1024, 256, 0, stream>>>(Wo, wob, 262144);
    cvt_bf16<<<4096, 256, 0, stream>>>(W1, w1b, 1048576);
    cvt_bf16<<<4096, 256, 0, stream>>>(W2, w2b, 1048576);

    // qkv = x @ Wqkv^T + bqkv  -> bf16 [4096, 3072]
    gemm_bt<1><<<dim3(24, 32), 256, 0, stream>>>(xbf, wqkvb, bqkv, qkvbf, MTOK, 3072, 1024);
    // attention -> ctx bf16 [4096, 1024]
    attn_fused<<<dim3(16, 64), 256, 0, stream>>>(qkvbf, mask, ctx);
    // attn_out = ctx @ Wo^T + bo -> f32
    gemm_bt<0><<<dim3(8, 32), 256, 0, stream>>>(ctx, wob, bo, attno, MTOK, 1024, 1024);
    // h = LN(attn_out + x)
    resid_ln<<<4096, 256, 0, stream>>>(attno, x, g1, be1, hf, hbf);
    // ff1 = relu(h @ W1^T + b1) -> bf16 [4096, 4096]
    gemm_bt<2><<<dim3(32, 32), 256, 0, stream>>>(hbf, w1b, b1, ff1, MTOK, FFN_DIM, 1024);
    // ff2 = ff1 @ W2^T + b2 -> f32 [4096, 1024]
    gemm_bt<0><<<dim3(8, 32), 256, 0, stream>>>(ff1, w2b, b2, ff2, MTOK, 1024, FFN_DIM);
    // out = LN(ff2 + h)
    resid_ln<<<4096, 256, 0, stream>>>(ff2, hf, g2, be2, out, nullptr);
}

// Round 2
// 415.227 us; speedup vs baseline: 1.1024x; 1.1024x over previous
//
#include <hip/hip_runtime.h>

#define DDIM 1024
#define FFN_DIM 4096
#define SS 1024
#define MTOK 4096  // B*S

typedef __bf16 bf16x8 __attribute__((ext_vector_type(8)));
typedef float f32x4 __attribute__((ext_vector_type(4)));
typedef unsigned short ushort4v __attribute__((ext_vector_type(4)));
typedef unsigned short ushort8v __attribute__((ext_vector_type(8)));

__device__ __forceinline__ unsigned short f2bf(float f) {
    union { float f; unsigned u; } x;
    x.f = f;
    unsigned r = x.u + 0x7FFFu + ((x.u >> 16) & 1u);
    return (unsigned short)(r >> 16);
}

// XOR swizzle for [rows][128B] LDS tiles: flips byte bits 4-6 by row bits.
// Involution (only reads bits >=7, modifies bits 4-6). 16B-alignment preserved.
__device__ __forceinline__ int swz(int off) {
    return off ^ ((((off >> 7) & 7) ^ ((off >> 10) & 1)) << 4);
}

// async global->LDS, 16B per lane. LDS dest = wave-uniform base + lane*16.
__device__ __forceinline__ void gload_lds16(const void* g, void* l) {
    __builtin_amdgcn_global_load_lds(
        (__attribute__((address_space(1))) unsigned int*)(unsigned long long)(g),
        (__attribute__((address_space(3))) unsigned int*)(l), 16, 0, 0);
}

// ---------------------------------------------------------------------------
// f32 -> bf16 conversion, 4 elems/thread
// ---------------------------------------------------------------------------
__global__ __launch_bounds__(256) void cvt_bf16(const float* __restrict__ in,
                                                unsigned short* __restrict__ out, int n4) {
    int i = blockIdx.x * 256 + threadIdx.x;
    if (i < n4) {
        float4 v = ((const float4*)in)[i];
        ushort4v u = {f2bf(v.x), f2bf(v.y), f2bf(v.z), f2bf(v.w)};
        ((ushort4v*)out)[i] = u;
    }
}

// ---------------------------------------------------------------------------
// C[M,N] = A[M,K] @ B[N,K]^T + bias  (bf16 in, f32 acc)
// EPI: 0 = f32 out, 1 = bf16 out, 2 = relu -> bf16 out
// BN: 128 (4 waves as 2x2 of 64x64) or 64 (2x2 of 64x32, for narrow N)
// BK=32 rows are 64B -> two rows cover all 32 banks; no swizzle needed.
// ---------------------------------------------------------------------------
template <int EPI, int BN>
__global__ __launch_bounds__(256) void gemm_bt(const unsigned short* __restrict__ A,
                                               const unsigned short* __restrict__ B,
                                               const float* __restrict__ bias,
                                               void* __restrict__ Cout,
                                               int M, int N, int K) {
    constexpr int NF = BN / 32;  // n-frags per wave
    __shared__ unsigned short Asm[128 * 32];
    __shared__ unsigned short Bsm[BN * 32];
    const int tid = threadIdx.x;
    const int wid = tid >> 6, lane = tid & 63;
    const int m0 = blockIdx.y * 128, n0 = blockIdx.x * BN;
    const int lr = lane & 15, lk = (lane >> 4) * 8;
    const int wr = (wid >> 1) * 64, wc = (wid & 1) * (BN / 2);

    f32x4 acc[4][NF];
#pragma unroll
    for (int i = 0; i < 4; i++)
#pragma unroll
        for (int j = 0; j < NF; j++) acc[i][j] = (f32x4){0.f, 0.f, 0.f, 0.f};

    const unsigned short* Ag = A + (size_t)m0 * K;
    const unsigned short* Bg = B + (size_t)n0 * K;

    for (int k0 = 0; k0 < K; k0 += 32) {
#pragma unroll
        for (int p = 0; p < 2; ++p) {
            int idx = p * 4096 + wid * 1024 + lane * 16;
            int row = idx >> 6, ce = (idx & 63) >> 1;
            gload_lds16(Ag + (size_t)row * K + k0 + ce, (char*)Asm + p * 4096 + wid * 1024);
        }
#pragma unroll
        for (int p = 0; p < BN / 64; ++p) {
            int idx = p * 4096 + wid * 1024 + lane * 16;
            int row = idx >> 6, ce = (idx & 63) >> 1;
            gload_lds16(Bg + (size_t)row * K + k0 + ce, (char*)Bsm + p * 4096 + wid * 1024);
        }
        __syncthreads();
        bf16x8 af[4], bfr[NF];
#pragma unroll
        for (int m = 0; m < 4; m++) af[m] = *(const bf16x8*)&Asm[(wr + m * 16 + lr) * 32 + lk];
#pragma unroll
        for (int n = 0; n < NF; n++) bfr[n] = *(const bf16x8*)&Bsm[(wc + n * 16 + lr) * 32 + lk];
#pragma unroll
        for (int m = 0; m < 4; m++)
#pragma unroll
            for (int n = 0; n < NF; n++)
                acc[m][n] = __builtin_amdgcn_mfma_f32_16x16x32_bf16(af[m], bfr[n], acc[m][n], 0, 0, 0);
        __syncthreads();
    }

    // epilogue: C/D layout col = lane&15, row = (lane>>4)*4 + reg
    float bv[NF];
#pragma unroll
    for (int n = 0; n < NF; n++) bv[n] = bias[n0 + wc + n * 16 + lr];
    const int r0 = (lane >> 4) * 4;
#pragma unroll
    for (int m = 0; m < 4; m++) {
#pragma unroll
        for (int n = 0; n < NF; n++) {
            int col = n0 + wc + n * 16 + lr;
#pragma unroll
            for (int r = 0; r < 4; r++) {
                int row = m0 + wr + m * 16 + r0 + r;
                float v = acc[m][n][r] + bv[n];
                if (EPI == 0) {
                    ((float*)Cout)[(size_t)row * N + col] = v;
                } else if (EPI == 1) {
                    ((unsigned short*)Cout)[(size_t)row * N + col] = f2bf(v);
                } else {
                    ((unsigned short*)Cout)[(size_t)row * N + col] = f2bf(fmaxf(v, 0.f));
                }
            }
        }
    }
}

// ---------------------------------------------------------------------------
// V transpose: qkv V-part [b,s,h,d] -> vt [b,h,d,s]  (bf16)
// One block per (64-token tile, b*h). LDS tile swizzled to keep both the
// vectorized writes and the strided transpose reads spread across banks.
// ---------------------------------------------------------------------------
__global__ __launch_bounds__(256) void vtrans(const unsigned short* __restrict__ qkv,
                                              unsigned short* __restrict__ vt) {
    __shared__ unsigned short T[64 * 64];
    const int tid = threadIdx.x;
    const int bh = blockIdx.y, b = bh >> 4, h = bh & 15;
    const int s0 = blockIdx.x * 64;
    const unsigned short* src = qkv + (size_t)(b * SS + s0) * 3072 + 2048 + h * 64;
#pragma unroll
    for (int p = 0; p < 2; p++) {
        int idx = p * 4096 + tid * 16;
        int row = idx >> 7, ce = (idx & 127) >> 1;
        ushort8v v = *(const ushort8v*)(src + (size_t)row * 3072 + ce);
        *(ushort8v*)((char*)T + swz(idx)) = v;
    }
    __syncthreads();
    unsigned short* dst = vt + (size_t)bh * 64 * SS + s0;
#pragma unroll
    for (int p = 0; p < 2; p++) {
        int idx = p * 4096 + tid * 16;
        int d = idx >> 7, t0 = (idx & 127) >> 1;
        ushort8v o;
#pragma unroll
        for (int i = 0; i < 8; i++)
            o[i] = *(const unsigned short*)((char*)T + swz((t0 + i) * 128 + d * 2));
        *(ushort8v*)(dst + (size_t)d * SS + t0) = o;
    }
}

// ---------------------------------------------------------------------------
// Flash attention. One block per (b,h,64-row q-tile); 4 waves, 16 q-rows each.
// K tiles from qkv (row-major [key][d]); V tiles from pre-transposed vt
// ([d][key]). Both staged via global_load_lds with pre-swizzled global source
// (linear LDS dest), read back with the same XOR swizzle. Double-buffered:
// stage(next) issued right after the single per-iteration barrier.
// ---------------------------------------------------------------------------
__global__ __launch_bounds__(256) void attn_fused(const unsigned short* __restrict__ qkv,
                                                  const unsigned short* __restrict__ vt,
                                                  const int* __restrict__ mask,
                                                  unsigned short* __restrict__ ctx) {
    __shared__ unsigned short Ksm[2][64 * 64];
    __shared__ unsigned short Vsm[2][64 * 64];
    __shared__ unsigned short Psm[4][16 * 64];
    __shared__ float maskadd[2][64];
    const int tid = threadIdx.x, wid = tid >> 6, lane = tid & 63;
    const int bh = blockIdx.y, b = bh >> 4, h = bh & 15;
    const int q0 = blockIdx.x * 64;
    const int lr = lane & 15, lk2 = (lane >> 4) * 16;  // byte offset of 8-elem k-group
    const size_t base = (size_t)b * SS * 3072 + h * 64;

    bf16x8 qf[2];
    {
        const unsigned short* qp = qkv + base + (size_t)(q0 + wid * 16 + lr) * 3072;
        qf[0] = *(const bf16x8*)(qp + (lk2 >> 1));
        qf[1] = *(const bf16x8*)(qp + 32 + (lk2 >> 1));
    }
    float m_run[4] = {-3e38f, -3e38f, -3e38f, -3e38f};
    float l_run[4] = {0.f, 0.f, 0.f, 0.f};
    f32x4 oacc[4];
#pragma unroll
    for (int i = 0; i < 4; i++) oacc[i] = (f32x4){0.f, 0.f, 0.f, 0.f};

    const unsigned short* Kgb = qkv + base + 1024;
    const unsigned short* Vgb = vt + (size_t)bh * 64 * SS;

    auto stage = [&](int buf, int kt) {
#pragma unroll
        for (int p = 0; p < 2; p++) {
            int idx = p * 4096 + wid * 1024 + lane * 16;
            int s = swz(idx);
            int row = s >> 7, ce = (s & 127) >> 1;
            gload_lds16(Kgb + (size_t)(kt * 64 + row) * 3072 + ce,
                        (char*)Ksm[buf] + p * 4096 + wid * 1024);
            gload_lds16(Vgb + (size_t)row * SS + kt * 64 + ce,
                        (char*)Vsm[buf] + p * 4096 + wid * 1024);
        }
        if (tid < 64) maskadd[buf][tid] = mask[bh * SS + kt * 64 + tid] ? 0.f : -1e9f;
    };

    stage(0, 0);
    for (int kt = 0; kt < SS / 64; ++kt) {
        const int cur = kt & 1;
        __syncthreads();  // implicit vmcnt(0): buf[cur] staged; prev reads done
        if (kt < SS / 64 - 1) stage(cur ^ 1, kt + 1);
        const char* Kb = (const char*)Ksm[cur];
        const char* Vb = (const char*)Vsm[cur];

        // scores: S = Q(16x64) @ K^T(64x64), per wave
        f32x4 sc[4];
#pragma unroll
        for (int nt = 0; nt < 4; nt++) {
            f32x4 a = (f32x4){0.f, 0.f, 0.f, 0.f};
            int rowb = (nt * 16 + lr) * 128;
            bf16x8 k0v = *(const bf16x8*)(Kb + swz(rowb + lk2));
            bf16x8 k1v = *(const bf16x8*)(Kb + swz(rowb + 64 + lk2));
            a = __builtin_amdgcn_mfma_f32_16x16x32_bf16(qf[0], k0v, a, 0, 0, 0);
            a = __builtin_amdgcn_mfma_f32_16x16x32_bf16(qf[1], k1v, a, 0, 0, 0);
            sc[nt] = a;
        }
        float mk[4];
#pragma unroll
        for (int nt = 0; nt < 4; nt++) mk[nt] = maskadd[cur][nt * 16 + lr];
#pragma unroll
        for (int r = 0; r < 4; r++) {
            float v = -3e38f;
#pragma unroll
            for (int nt = 0; nt < 4; nt++) {
                float s = sc[nt][r] * 0.125f + mk[nt];
                sc[nt][r] = s;
                v = fmaxf(v, s);
            }
            v = fmaxf(v, __shfl_xor(v, 1));
            v = fmaxf(v, __shfl_xor(v, 2));
            v = fmaxf(v, __shfl_xor(v, 4));
            v = fmaxf(v, __shfl_xor(v, 8));
            float mnew = fmaxf(m_run[r], v);
            float alpha = __expf(m_run[r] - mnew);
            m_run[r] = mnew;
            float ls = 0.f;
#pragma unroll
            for (int nt = 0; nt < 4; nt++) {
                float pexp = __expf(sc[nt][r] - mnew);
                sc[nt][r] = pexp;
                ls += pexp;
            }
            ls += __shfl_xor(ls, 1);
            ls += __shfl_xor(ls, 2);
            ls += __shfl_xor(ls, 4);
            ls += __shfl_xor(ls, 8);
            l_run[r] = l_run[r] * alpha + ls;
#pragma unroll
            for (int dt = 0; dt < 4; dt++) oacc[dt][r] *= alpha;
        }
        // P -> bf16 -> per-wave LDS (swizzled), then PV
        const int prow = (lane >> 4) * 4;
        char* Pb = (char*)Psm[wid];
#pragma unroll
        for (int nt = 0; nt < 4; nt++)
#pragma unroll
            for (int r = 0; r < 4; r++)
                *(unsigned short*)(Pb + swz((prow + r) * 128 + (nt * 16 + lr) * 2)) = f2bf(sc[nt][r]);
        bf16x8 pf0 = *(const bf16x8*)(Pb + swz(lr * 128 + lk2));
        bf16x8 pf1 = *(const bf16x8*)(Pb + swz(lr * 128 + 64 + lk2));
#pragma unroll
        for (int dt = 0; dt < 4; dt++) {
            int rowb = (dt * 16 + lr) * 128;
            bf16x8 v0 = *(const bf16x8*)(Vb + swz(rowb + lk2));
            bf16x8 v1 = *(const bf16x8*)(Vb + swz(rowb + 64 + lk2));
            oacc[dt] = __builtin_amdgcn_mfma_f32_16x16x32_bf16(pf0, v0, oacc[dt], 0, 0, 0);
            oacc[dt] = __builtin_amdgcn_mfma_f32_16x16x32_bf16(pf1, v1, oacc[dt], 0, 0, 0);
        }
    }
#pragma unroll
    for (int dt = 0; dt < 4; dt++) {
#pragma unroll
        for (int r = 0; r < 4; r++) {
            float v = oacc[dt][r] / l_run[r];
            int row = q0 + wid * 16 + (lane >> 4) * 4 + r;
            ctx[(size_t)(b * SS + row) * DDIM + h * 64 + dt * 16 + lr] = f2bf(v);
        }
    }
}

// ---------------------------------------------------------------------------
// out = LayerNorm(a + b) * gamma + beta, row-wise over D=1024.
// ---------------------------------------------------------------------------
__global__ __launch_bounds__(256) void resid_ln(const float* __restrict__ a,
                                                const float* __restrict__ b,
                                                const float* __restrict__ gamma,
                                                const float* __restrict__ beta,
                                                float* __restrict__ of32,
                                                unsigned short* __restrict__ obf) {
    __shared__ float red[16];
    const int row = blockIdx.x, tid = threadIdx.x;
    const int wid = tid >> 6, lane = tid & 63;
    float4 av = ((const float4*)(a + (size_t)row * DDIM))[tid];
    float4 bv = ((const float4*)(b + (size_t)row * DDIM))[tid];
    float4 v;
    v.x = av.x + bv.x; v.y = av.y + bv.y; v.z = av.z + bv.z; v.w = av.w + bv.w;
    float s = v.x + v.y + v.z + v.w;
    float s2 = v.x * v.x + v.y * v.y + v.z * v.z + v.w * v.w;
#pragma unroll
    for (int off = 1; off < 64; off <<= 1) {
        s += __shfl_xor(s, off);
        s2 += __shfl_xor(s2, off);
    }
    if (lane == 0) { red[wid] = s; red[8 + wid] = s2; }
    __syncthreads();
    s = red[0] + red[1] + red[2] + red[3];
    s2 = red[8] + red[9] + red[10] + red[11];
    float mean = s * (1.f / 1024.f);
    float var = s2 * (1.f / 1024.f) - mean * mean;
    float rstd = rsqrtf(var + 1e-12f);
    float4 g = ((const float4*)gamma)[tid];
    float4 be = ((const float4*)beta)[tid];
    float4 o;
    o.x = g.x * (v.x - mean) * rstd + be.x;
    o.y = g.y * (v.y - mean) * rstd + be.y;
    o.z = g.z * (v.z - mean) * rstd + be.z;
    o.w = g.w * (v.w - mean) * rstd + be.w;
    if (of32) ((float4*)(of32 + (size_t)row * DDIM))[tid] = o;
    if (obf) {
        ushort4v u = {f2bf(o.x), f2bf(o.y), f2bf(o.z), f2bf(o.w)};
        ((ushort4v*)(obf + (size_t)row * DDIM))[tid] = u;
    }
}

// ---------------------------------------------------------------------------
extern "C" void kernel_launch(void* const* d_in, const int* in_sizes, int n_in,
                              void* d_out, int out_size, void* d_ws, size_t ws_size,
                              hipStream_t stream) {
    const float* x    = (const float*)d_in[0];
    const int*   mask = (const int*)d_in[1];
    const float* Wqkv = (const float*)d_in[2];
    const float* bqkv = (const float*)d_in[3];
    const float* Wo   = (const float*)d_in[4];
    const float* bo   = (const float*)d_in[5];
    const float* W1   = (const float*)d_in[6];
    const float* b1   = (const float*)d_in[7];
    const float* W2   = (const float*)d_in[8];
    const float* b2   = (const float*)d_in[9];
    const float* g1   = (const float*)d_in[10];
    const float* be1  = (const float*)d_in[11];
    const float* g2   = (const float*)d_in[12];
    const float* be2  = (const float*)d_in[13];
    float* out = (float*)d_out;

    // workspace layout (104 MB total, lifetime-overlapped):
    //   [0,8)    xbf (dead after QKV gemm) -> vtb (dead after attn) -> ff1 lo
    //   [8,32)   qkvbf (dead after attn) -> ff1 hi
    //   [32,40)  ctx; [40,64) weights bf16; [64,80) attno/ff2; [80,96) hf; [96,104) hbf
    char* ws = (char*)d_ws;
    unsigned short* xbf   = (unsigned short*)(ws + 0);
    unsigned short* vtb   = (unsigned short*)(ws + 0);
    unsigned short* ff1   = (unsigned short*)(ws + 0);
    unsigned short* qkvbf = (unsigned short*)(ws + (8ull << 20));
    unsigned short* ctx   = (unsigned short*)(ws + (32ull << 20));
    unsigned short* wqkvb = (unsigned short*)(ws + (40ull << 20));
    unsigned short* wob   = (unsigned short*)(ws + (46ull << 20));
    unsigned short* w1b   = (unsigned short*)(ws + (48ull << 20));
    unsigned short* w2b   = (unsigned short*)(ws + (56ull << 20));
    float* attno          = (float*)(ws + (64ull << 20));
    float* ff2            = (float*)(ws + (64ull << 20));
    float* hf             = (float*)(ws + (80ull << 20));
    unsigned short* hbf   = (unsigned short*)(ws + (96ull << 20));

    cvt_bf16<<<4096, 256, 0, stream>>>(x, xbf, 1048576);
    cvt_bf16<<<3072, 256, 0, stream>>>(Wqkv, wqkvb, 786432);
    cvt_bf16<<<1024, 256, 0, stream>>>(Wo, wob, 262144);
    cvt_bf16<<<4096, 256, 0, stream>>>(W1, w1b, 1048576);
    cvt_bf16<<<4096, 256, 0, stream>>>(W2, w2b, 1048576);

    // qkv = x @ Wqkv^T + bqkv  -> bf16 [4096, 3072]
    gemm_bt<1, 128><<<dim3(24, 32), 256, 0, stream>>>(xbf, wqkvb, bqkv, qkvbf, MTOK, 3072, 1024);
    // vt[b,h,d,s] = V^T (xbf region is dead now)
    vtrans<<<dim3(16, 64), 256, 0, stream>>>(qkvbf, vtb);
    // attention -> ctx bf16 [4096, 1024]
    attn_fused<<<dim3(16, 64), 256, 0, stream>>>(qkvbf, vtb, mask, ctx);
    // attn_out = ctx @ Wo^T + bo -> f32
    gemm_bt<0, 64><<<dim3(16, 32), 256, 0, stream>>>(ctx, wob, bo, attno, MTOK, 1024, 1024);
    // h = LN(attn_out + x)
    resid_ln<<<4096, 256, 0, stream>>>(attno, x, g1, be1, hf, hbf);
    // ff1 = relu(h @ W1^T + b1) -> bf16 [4096, 4096]
    gemm_bt<2, 128><<<dim3(32, 32), 256, 0, stream>>>(hbf, w1b, b1, ff1, MTOK, FFN_DIM, 1024);
    // ff2 = ff1 @ W2^T + b2 -> f32 [4096, 1024]
    gemm_bt<0, 64><<<dim3(16, 32), 256, 0, stream>>>(ff1, w2b, b2, ff2, MTOK, 1024, FFN_DIM);
    // out = LN(ff2 + h)
    resid_ln<<<4096, 256, 0, stream>>>(ff2, hf, g2, be2, out, nullptr);
}

// Round 3
// 382.114 us; speedup vs baseline: 1.1979x; 1.0867x over previous
//
#include <hip/hip_runtime.h>

#define DDIM 1024
#define FFN_DIM 4096
#define SS 1024
#define MTOK 4096  // B*S

typedef __bf16 bf16x8 __attribute__((ext_vector_type(8)));
typedef float f32x4 __attribute__((ext_vector_type(4)));
typedef unsigned short ushort4v __attribute__((ext_vector_type(4)));
typedef unsigned short ushort8v __attribute__((ext_vector_type(8)));

__device__ __forceinline__ unsigned short f2bf(float f) {
    union { float f; unsigned u; } x;
    x.f = f;
    unsigned r = x.u + 0x7FFFu + ((x.u >> 16) & 1u);
    return (unsigned short)(r >> 16);
}
__device__ __forceinline__ float bf2f(unsigned short u) {
    union { unsigned u; float f; } x;
    x.u = (unsigned)u << 16;
    return x.f;
}

// XOR swizzle for [rows][128B] LDS tiles (attention): involution on bits 4-6.
__device__ __forceinline__ int swz(int off) {
    return off ^ ((((off >> 7) & 7) ^ ((off >> 10) & 1)) << 4);
}

// async global->LDS, 16B per lane. LDS dest = wave-uniform base + lane*16.
__device__ __forceinline__ void gload_lds16(const void* g, void* l) {
    __builtin_amdgcn_global_load_lds(
        (__attribute__((address_space(1))) unsigned int*)(unsigned long long)(g),
        (__attribute__((address_space(3))) unsigned int*)(l), 16, 0, 0);
}

// ---------------------------------------------------------------------------
// f32 -> bf16 conversion, 4 elems/thread
// ---------------------------------------------------------------------------
__global__ __launch_bounds__(256) void cvt_bf16(const float* __restrict__ in,
                                                unsigned short* __restrict__ out, int n4) {
    int i = blockIdx.x * 256 + threadIdx.x;
    if (i < n4) {
        float4 v = ((const float4*)in)[i];
        ushort4v u = {f2bf(v.x), f2bf(v.y), f2bf(v.z), f2bf(v.w)};
        ((ushort4v*)out)[i] = u;
    }
}

// ---------------------------------------------------------------------------
// C[M,N] = A[M,K] @ B[N,K]^T (+ bias on z==0)  (bf16 in, f32 acc)
// EPI: 1 = bf16 out, 2 = relu -> bf16 out
// 128x128 tile, BK=32, double-buffered LDS (32 KB), single barrier per K-step:
//   barrier (drains stage of buf[cur]) -> issue stage(buf[cur^1]) -> ds_read
//   buf[cur] -> MFMA. Loads for tile t+1 fly under tile t's compute.
// SPLITK: blockIdx.z selects a K-chunk; partial written to Cout + z*M*N.
// ---------------------------------------------------------------------------
template <int EPI, int SPLITK>
__global__ __launch_bounds__(256) void gemm_bt(const unsigned short* __restrict__ A,
                                               const unsigned short* __restrict__ B,
                                               const float* __restrict__ bias,
                                               unsigned short* __restrict__ Cout,
                                               int M, int N, int K) {
    __shared__ unsigned short Asm[2][128 * 32];
    __shared__ unsigned short Bsm[2][128 * 32];
    const int tid = threadIdx.x;
    const int wid = tid >> 6, lane = tid & 63;
    const int m0 = blockIdx.y * 128, n0 = blockIdx.x * 128;
    const int lr = lane & 15, lk = (lane >> 4) * 8;
    const int wr = (wid >> 1) * 64, wc = (wid & 1) * 64;
    const int Kper = K / SPLITK;
    const int kbase = blockIdx.z * Kper;
    const int nkt = Kper / 32;

    f32x4 acc[4][4];
#pragma unroll
    for (int i = 0; i < 4; i++)
#pragma unroll
        for (int j = 0; j < 4; j++) acc[i][j] = (f32x4){0.f, 0.f, 0.f, 0.f};

    const unsigned short* Ag = A + (size_t)m0 * K;
    const unsigned short* Bg = B + (size_t)n0 * K;

    auto stage = [&](int buf, int k0) {
#pragma unroll
        for (int p = 0; p < 2; ++p) {
            int idx = p * 4096 + wid * 1024 + lane * 16;
            int row = idx >> 6, ce = (idx & 63) >> 1;
            gload_lds16(Ag + (size_t)row * K + k0 + ce, (char*)Asm[buf] + p * 4096 + wid * 1024);
            gload_lds16(Bg + (size_t)row * K + k0 + ce, (char*)Bsm[buf] + p * 4096 + wid * 1024);
        }
    };

    stage(0, kbase);
    for (int kt = 0; kt < nkt; ++kt) {
        const int cur = kt & 1;
        __syncthreads();  // compiler emits vmcnt(0)+lgkmcnt(0) drain: buf[cur] staged
        if (kt + 1 < nkt) stage(cur ^ 1, kbase + (kt + 1) * 32);
        bf16x8 af[4], bfr[4];
#pragma unroll
        for (int m = 0; m < 4; m++) af[m] = *(const bf16x8*)&Asm[cur][(wr + m * 16 + lr) * 32 + lk];
#pragma unroll
        for (int n = 0; n < 4; n++) bfr[n] = *(const bf16x8*)&Bsm[cur][(wc + n * 16 + lr) * 32 + lk];
#pragma unroll
        for (int m = 0; m < 4; m++)
#pragma unroll
            for (int n = 0; n < 4; n++)
                acc[m][n] = __builtin_amdgcn_mfma_f32_16x16x32_bf16(af[m], bfr[n], acc[m][n], 0, 0, 0);
    }

    // epilogue: C/D layout col = lane&15, row = (lane>>4)*4 + reg
    unsigned short* Op = Cout + (size_t)blockIdx.z * M * N;
    float bv[4];
    const bool hasb = (SPLITK == 1) || (blockIdx.z == 0);
#pragma unroll
    for (int n = 0; n < 4; n++) bv[n] = hasb ? bias[n0 + wc + n * 16 + lr] : 0.f;
    const int r0 = (lane >> 4) * 4;
#pragma unroll
    for (int m = 0; m < 4; m++) {
#pragma unroll
        for (int n = 0; n < 4; n++) {
            int col = n0 + wc + n * 16 + lr;
#pragma unroll
            for (int r = 0; r < 4; r++) {
                int row = m0 + wr + m * 16 + r0 + r;
                float v = acc[m][n][r] + bv[n];
                if (EPI == 2) v = fmaxf(v, 0.f);
                Op[(size_t)row * N + col] = f2bf(v);
            }
        }
    }
}

// ---------------------------------------------------------------------------
// V transpose: qkv V-part [b,s,h,d] -> vt [b,h,d,s]  (bf16)
// ---------------------------------------------------------------------------
__global__ __launch_bounds__(256) void vtrans(const unsigned short* __restrict__ qkv,
                                              unsigned short* __restrict__ vt) {
    __shared__ unsigned short T[64 * 64];
    const int tid = threadIdx.x;
    const int bh = blockIdx.y, b = bh >> 4, h = bh & 15;
    const int s0 = blockIdx.x * 64;
    const unsigned short* src = qkv + (size_t)(b * SS + s0) * 3072 + 2048 + h * 64;
#pragma unroll
    for (int p = 0; p < 2; p++) {
        int idx = p * 4096 + tid * 16;
        int row = idx >> 7, ce = (idx & 127) >> 1;
        ushort8v v = *(const ushort8v*)(src + (size_t)row * 3072 + ce);
        *(ushort8v*)((char*)T + swz(idx)) = v;
    }
    __syncthreads();
    unsigned short* dst = vt + (size_t)bh * 64 * SS + s0;
#pragma unroll
    for (int p = 0; p < 2; p++) {
        int idx = p * 4096 + tid * 16;
        int d = idx >> 7, t0 = (idx & 127) >> 1;
        ushort8v o;
#pragma unroll
        for (int i = 0; i < 8; i++)
            o[i] = *(const unsigned short*)((char*)T + swz((t0 + i) * 128 + d * 2));
        *(ushort8v*)(dst + (size_t)d * SS + t0) = o;
    }
}

// ---------------------------------------------------------------------------
// Flash attention (unchanged from round 2: swizzled K/V/P, dbuf, 1 barrier).
// ---------------------------------------------------------------------------
__global__ __launch_bounds__(256) void attn_fused(const unsigned short* __restrict__ qkv,
                                                  const unsigned short* __restrict__ vt,
                                                  const int* __restrict__ mask,
                                                  unsigned short* __restrict__ ctx) {
    __shared__ unsigned short Ksm[2][64 * 64];
    __shared__ unsigned short Vsm[2][64 * 64];
    __shared__ unsigned short Psm[4][16 * 64];
    __shared__ float maskadd[2][64];
    const int tid = threadIdx.x, wid = tid >> 6, lane = tid & 63;
    const int bh = blockIdx.y, b = bh >> 4, h = bh & 15;
    const int q0 = blockIdx.x * 64;
    const int lr = lane & 15, lk2 = (lane >> 4) * 16;
    const size_t base = (size_t)b * SS * 3072 + h * 64;

    bf16x8 qf[2];
    {
        const unsigned short* qp = qkv + base + (size_t)(q0 + wid * 16 + lr) * 3072;
        qf[0] = *(const bf16x8*)(qp + (lk2 >> 1));
        qf[1] = *(const bf16x8*)(qp + 32 + (lk2 >> 1));
    }
    float m_run[4] = {-3e38f, -3e38f, -3e38f, -3e38f};
    float l_run[4] = {0.f, 0.f, 0.f, 0.f};
    f32x4 oacc[4];
#pragma unroll
    for (int i = 0; i < 4; i++) oacc[i] = (f32x4){0.f, 0.f, 0.f, 0.f};

    const unsigned short* Kgb = qkv + base + 1024;
    const unsigned short* Vgb = vt + (size_t)bh * 64 * SS;

    auto stage = [&](int buf, int kt) {
#pragma unroll
        for (int p = 0; p < 2; p++) {
            int idx = p * 4096 + wid * 1024 + lane * 16;
            int s = swz(idx);
            int row = s >> 7, ce = (s & 127) >> 1;
            gload_lds16(Kgb + (size_t)(kt * 64 + row) * 3072 + ce,
                        (char*)Ksm[buf] + p * 4096 + wid * 1024);
            gload_lds16(Vgb + (size_t)row * SS + kt * 64 + ce,
                        (char*)Vsm[buf] + p * 4096 + wid * 1024);
        }
        if (tid < 64) maskadd[buf][tid] = mask[bh * SS + kt * 64 + tid] ? 0.f : -1e9f;
    };

    stage(0, 0);
    for (int kt = 0; kt < SS / 64; ++kt) {
        const int cur = kt & 1;
        __syncthreads();
        if (kt < SS / 64 - 1) stage(cur ^ 1, kt + 1);
        const char* Kb = (const char*)Ksm[cur];
        const char* Vb = (const char*)Vsm[cur];

        f32x4 sc[4];
#pragma unroll
        for (int nt = 0; nt < 4; nt++) {
            f32x4 a = (f32x4){0.f, 0.f, 0.f, 0.f};
            int rowb = (nt * 16 + lr) * 128;
            bf16x8 k0v = *(const bf16x8*)(Kb + swz(rowb + lk2));
            bf16x8 k1v = *(const bf16x8*)(Kb + swz(rowb + 64 + lk2));
            a = __builtin_amdgcn_mfma_f32_16x16x32_bf16(qf[0], k0v, a, 0, 0, 0);
            a = __builtin_amdgcn_mfma_f32_16x16x32_bf16(qf[1], k1v, a, 0, 0, 0);
            sc[nt] = a;
        }
        float mk[4];
#pragma unroll
        for (int nt = 0; nt < 4; nt++) mk[nt] = maskadd[cur][nt * 16 + lr];
#pragma unroll
        for (int r = 0; r < 4; r++) {
            float v = -3e38f;
#pragma unroll
            for (int nt = 0; nt < 4; nt++) {
                float s = sc[nt][r] * 0.125f + mk[nt];
                sc[nt][r] = s;
                v = fmaxf(v, s);
            }
            v = fmaxf(v, __shfl_xor(v, 1));
            v = fmaxf(v, __shfl_xor(v, 2));
            v = fmaxf(v, __shfl_xor(v, 4));
            v = fmaxf(v, __shfl_xor(v, 8));
            float mnew = fmaxf(m_run[r], v);
            float alpha = __expf(m_run[r] - mnew);
            m_run[r] = mnew;
            float ls = 0.f;
#pragma unroll
            for (int nt = 0; nt < 4; nt++) {
                float pexp = __expf(sc[nt][r] - mnew);
                sc[nt][r] = pexp;
                ls += pexp;
            }
            ls += __shfl_xor(ls, 1);
            ls += __shfl_xor(ls, 2);
            ls += __shfl_xor(ls, 4);
            ls += __shfl_xor(ls, 8);
            l_run[r] = l_run[r] * alpha + ls;
#pragma unroll
            for (int dt = 0; dt < 4; dt++) oacc[dt][r] *= alpha;
        }
        const int prow = (lane >> 4) * 4;
        char* Pb = (char*)Psm[wid];
#pragma unroll
        for (int nt = 0; nt < 4; nt++)
#pragma unroll
            for (int r = 0; r < 4; r++)
                *(unsigned short*)(Pb + swz((prow + r) * 128 + (nt * 16 + lr) * 2)) = f2bf(sc[nt][r]);
        bf16x8 pf0 = *(const bf16x8*)(Pb + swz(lr * 128 + lk2));
        bf16x8 pf1 = *(const bf16x8*)(Pb + swz(lr * 128 + 64 + lk2));
#pragma unroll
        for (int dt = 0; dt < 4; dt++) {
            int rowb = (dt * 16 + lr) * 128;
            bf16x8 v0 = *(const bf16x8*)(Vb + swz(rowb + lk2));
            bf16x8 v1 = *(const bf16x8*)(Vb + swz(rowb + 64 + lk2));
            oacc[dt] = __builtin_amdgcn_mfma_f32_16x16x32_bf16(pf0, v0, oacc[dt], 0, 0, 0);
            oacc[dt] = __builtin_amdgcn_mfma_f32_16x16x32_bf16(pf1, v1, oacc[dt], 0, 0, 0);
        }
    }
#pragma unroll
    for (int dt = 0; dt < 4; dt++) {
#pragma unroll
        for (int r = 0; r < 4; r++) {
            float v = oacc[dt][r] / l_run[r];
            int row = q0 + wid * 16 + (lane >> 4) * 4 + r;
            ctx[(size_t)(b * SS + row) * DDIM + h * 64 + dt * 16 + lr] = f2bf(v);
        }
    }
}

// ---------------------------------------------------------------------------
// LN1: h = LN(bf2f(attno) + x) -> bf16
// ---------------------------------------------------------------------------
__global__ __launch_bounds__(256) void resid_ln1(const unsigned short* __restrict__ attno,
                                                 const float* __restrict__ x,
                                                 const float* __restrict__ gamma,
                                                 const float* __restrict__ beta,
                                                 unsigned short* __restrict__ hbf) {
    __shared__ float red[16];
    const int row = blockIdx.x, tid = threadIdx.x;
    const int wid = tid >> 6, lane = tid & 63;
    ushort4v av = ((const ushort4v*)(attno + (size_t)row * DDIM))[tid];
    float4 bv = ((const float4*)(x + (size_t)row * DDIM))[tid];
    float4 v;
    v.x = bf2f(av[0]) + bv.x; v.y = bf2f(av[1]) + bv.y;
    v.z = bf2f(av[2]) + bv.z; v.w = bf2f(av[3]) + bv.w;
    float s = v.x + v.y + v.z + v.w;
    float s2 = v.x * v.x + v.y * v.y + v.z * v.z + v.w * v.w;
#pragma unroll
    for (int off = 1; off < 64; off <<= 1) { s += __shfl_xor(s, off); s2 += __shfl_xor(s2, off); }
    if (lane == 0) { red[wid] = s; red[8 + wid] = s2; }
    __syncthreads();
    s = red[0] + red[1] + red[2] + red[3];
    s2 = red[8] + red[9] + red[10] + red[11];
    float mean = s * (1.f / 1024.f);
    float var = s2 * (1.f / 1024.f) - mean * mean;
    float rstd = rsqrtf(var + 1e-12f);
    float4 g = ((const float4*)gamma)[tid];
    float4 be = ((const float4*)beta)[tid];
    ushort4v u = {f2bf(g.x * (v.x - mean) * rstd + be.x),
                  f2bf(g.y * (v.y - mean) * rstd + be.y),
                  f2bf(g.z * (v.z - mean) * rstd + be.z),
                  f2bf(g.w * (v.w - mean) * rstd + be.w)};
    ((ushort4v*)(hbf + (size_t)row * DDIM))[tid] = u;
}

// ---------------------------------------------------------------------------
// LN2: out = LN(bf2f(p0) + bf2f(p1) + bf2f(h)) -> f32 (fused split-K reduce)
// ---------------------------------------------------------------------------
__global__ __launch_bounds__(256) void resid_ln2(const unsigned short* __restrict__ p0,
                                                 const unsigned short* __restrict__ p1,
                                                 const unsigned short* __restrict__ hbf,
                                                 const float* __restrict__ gamma,
                                                 const float* __restrict__ beta,
                                                 float* __restrict__ out) {
    __shared__ float red[16];
    const int row = blockIdx.x, tid = threadIdx.x;
    const int wid = tid >> 6, lane = tid & 63;
    ushort4v a0 = ((const ushort4v*)(p0 + (size_t)row * DDIM))[tid];
    ushort4v a1 = ((const ushort4v*)(p1 + (size_t)row * DDIM))[tid];
    ushort4v hv = ((const ushort4v*)(hbf + (size_t)row * DDIM))[tid];
    float4 v;
    v.x = bf2f(a0[0]) + bf2f(a1[0]) + bf2f(hv[0]);
    v.y = bf2f(a0[1]) + bf2f(a1[1]) + bf2f(hv[1]);
    v.z = bf2f(a0[2]) + bf2f(a1[2]) + bf2f(hv[2]);
    v.w = bf2f(a0[3]) + bf2f(a1[3]) + bf2f(hv[3]);
    float s = v.x + v.y + v.z + v.w;
    float s2 = v.x * v.x + v.y * v.y + v.z * v.z + v.w * v.w;
#pragma unroll
    for (int off = 1; off < 64; off <<= 1) { s += __shfl_xor(s, off); s2 += __shfl_xor(s2, off); }
    if (lane == 0) { red[wid] = s; red[8 + wid] = s2; }
    __syncthreads();
    s = red[0] + red[1] + red[2] + red[3];
    s2 = red[8] + red[9] + red[10] + red[11];
    float mean = s * (1.f / 1024.f);
    float var = s2 * (1.f / 1024.f) - mean * mean;
    float rstd = rsqrtf(var + 1e-12f);
    float4 g = ((const float4*)gamma)[tid];
    float4 be = ((const float4*)beta)[tid];
    float4 o;
    o.x = g.x * (v.x - mean) * rstd + be.x;
    o.y = g.y * (v.y - mean) * rstd + be.y;
    o.z = g.z * (v.z - mean) * rstd + be.z;
    o.w = g.w * (v.w - mean) * rstd + be.w;
    ((float4*)(out + (size_t)row * DDIM))[tid] = o;
}

// ---------------------------------------------------------------------------
extern "C" void kernel_launch(void* const* d_in, const int* in_sizes, int n_in,
                              void* d_out, int out_size, void* d_ws, size_t ws_size,
                              hipStream_t stream) {
    const float* x    = (const float*)d_in[0];
    const int*   mask = (const int*)d_in[1];
    const float* Wqkv = (const float*)d_in[2];
    const float* bqkv = (const float*)d_in[3];
    const float* Wo   = (const float*)d_in[4];
    const float* bo   = (const float*)d_in[5];
    const float* W1   = (const float*)d_in[6];
    const float* b1   = (const float*)d_in[7];
    const float* W2   = (const float*)d_in[8];
    const float* b2   = (const float*)d_in[9];
    const float* g1   = (const float*)d_in[10];
    const float* be1  = (const float*)d_in[11];
    const float* g2   = (const float*)d_in[12];
    const float* be2  = (const float*)d_in[13];
    float* out = (float*)d_out;

    // workspace (96 MB, lifetime-overlapped):
    // [0,8)   xbf -> vtb
    // [8,32)  qkvbf -> ff1-lo       [32,40) ctx -> ff1-hi   (ff1 = [8,40))
    // [40,48) w1b                   [48,56) w2b
    // [56,62) wqkvb                 [62,64) wob
    // [64,72) attno bf16            [72,80) hbf
    // [80,96) FFN2 partials bf16 (2 x 8 MB, z-indexed)
    char* ws = (char*)d_ws;
    unsigned short* xbf   = (unsigned short*)(ws + 0);
    unsigned short* vtb   = (unsigned short*)(ws + 0);
    unsigned short* qkvbf = (unsigned short*)(ws + (8ull << 20));
    unsigned short* ff1   = (unsigned short*)(ws + (8ull << 20));
    unsigned short* ctx   = (unsigned short*)(ws + (32ull << 20));
    unsigned short* w1b   = (unsigned short*)(ws + (40ull << 20));
    unsigned short* w2b   = (unsigned short*)(ws + (48ull << 20));
    unsigned short* wqkvb = (unsigned short*)(ws + (56ull << 20));
    unsigned short* wob   = (unsigned short*)(ws + (62ull << 20));
    unsigned short* attno = (unsigned short*)(ws + (64ull << 20));
    unsigned short* hbf   = (unsigned short*)(ws + (72ull << 20));
    unsigned short* pff   = (unsigned short*)(ws + (80ull << 20));

    cvt_bf16<<<4096, 256, 0, stream>>>(x, xbf, 1048576);
    cvt_bf16<<<3072, 256, 0, stream>>>(Wqkv, wqkvb, 786432);
    cvt_bf16<<<1024, 256, 0, stream>>>(Wo, wob, 262144);
    cvt_bf16<<<4096, 256, 0, stream>>>(W1, w1b, 1048576);
    cvt_bf16<<<4096, 256, 0, stream>>>(W2, w2b, 1048576);

    // qkv = x @ Wqkv^T + bqkv -> bf16 [4096, 3072]
    gemm_bt<1, 1><<<dim3(24, 32), 256, 0, stream>>>(xbf, wqkvb, bqkv, qkvbf, MTOK, 3072, 1024);
    vtrans<<<dim3(16, 64), 256, 0, stream>>>(qkvbf, vtb);
    attn_fused<<<dim3(16, 64), 256, 0, stream>>>(qkvbf, vtb, mask, ctx);
    // attn_out = ctx @ Wo^T + bo -> bf16
    gemm_bt<1, 1><<<dim3(8, 32), 256, 0, stream>>>(ctx, wob, bo, attno, MTOK, 1024, 1024);
    // h = LN(attn_out + x) -> bf16
    resid_ln1<<<4096, 256, 0, stream>>>(attno, x, g1, be1, hbf);
    // ff1 = relu(h @ W1^T + b1) -> bf16 [4096, 4096]
    gemm_bt<2, 1><<<dim3(32, 32), 256, 0, stream>>>(hbf, w1b, b1, ff1, MTOK, FFN_DIM, 1024);
    // ff2 partials (split-K x2): p_z = ff1 @ W2^T[kchunk z] (+b2 on z0) -> bf16
    gemm_bt<1, 2><<<dim3(8, 32, 2), 256, 0, stream>>>(ff1, w2b, b2, pff, MTOK, 1024, FFN_DIM);
    // out = LN(p0 + p1 + h)
    resid_ln2<<<4096, 256, 0, stream>>>(pff, pff + (size_t)MTOK * DDIM, hbf, g2, be2, out);
}

// Round 4
// 372.222 us; speedup vs baseline: 1.2297x; 1.0266x over previous
//
#include <hip/hip_runtime.h>

#define DDIM 1024
#define FFN_DIM 4096
#define SS 1024
#define MTOK 4096  // B*S

typedef __bf16 bf16x8 __attribute__((ext_vector_type(8)));
typedef float f32x4 __attribute__((ext_vector_type(4)));
typedef unsigned short ushort4v __attribute__((ext_vector_type(4)));
typedef unsigned short ushort8v __attribute__((ext_vector_type(8)));

__device__ __forceinline__ unsigned short f2bf(float f) {
    union { float f; unsigned u; } x;
    x.f = f;
    unsigned r = x.u + 0x7FFFu + ((x.u >> 16) & 1u);
    return (unsigned short)(r >> 16);
}
__device__ __forceinline__ float bf2f(unsigned short u) {
    union { unsigned u; float f; } x;
    x.u = (unsigned)u << 16;
    return x.f;
}

// attention-tile swizzle (rows of 128B): involution on bits 4-6
__device__ __forceinline__ int swz(int off) {
    return off ^ ((((off >> 7) & 7) ^ ((off >> 10) & 1)) << 4);
}
// gemm256 tile swizzle: XOR 16B-slot (bits 4-6) by row bits 0-2 (bits 7-9).
// 2-way floor on 16-lane column reads; involution.
__device__ __forceinline__ int gswz(int b) {
    return b ^ (((b >> 7) & 7) << 4);
}

// async global->LDS, 16B per lane. LDS dest = wave-uniform base + lane*16.
__device__ __forceinline__ void gload_lds16(const void* g, void* l) {
    __builtin_amdgcn_global_load_lds(
        (__attribute__((address_space(1))) unsigned int*)(unsigned long long)(g),
        (__attribute__((address_space(3))) unsigned int*)(l), 16, 0, 0);
}

// ---------------------------------------------------------------------------
__global__ __launch_bounds__(256) void cvt_bf16(const float* __restrict__ in,
                                                unsigned short* __restrict__ out, int n4) {
    int i = blockIdx.x * 256 + threadIdx.x;
    if (i < n4) {
        float4 v = ((const float4*)in)[i];
        ushort4v u = {f2bf(v.x), f2bf(v.y), f2bf(v.z), f2bf(v.w)};
        ((ushort4v*)out)[i] = u;
    }
}

// ---------------------------------------------------------------------------
// 256x256 8-wave 4-phase GEMM: C[M,N] = A[M,K] @ B[N,K]^T (+bias on z==0)
// bf16 in/out, f32 acc. EPI: 1 = bf16, 2 = relu->bf16.
// Double-buffered 128KB LDS; per K-tile: 4 phases, each {ds_read frags |
// stage 1 half-tile of t+1 | barrier | lgkm0 | setprio1 16xMFMA setprio0 |
// (p3: vmcnt0) barrier}. T2 swizzle both-sides; T5 setprio; T3/T4 schedule.
// ---------------------------------------------------------------------------
template <int EPI, int SPLITK>
__global__ __launch_bounds__(512, 2) void gemm256(const unsigned short* __restrict__ A,
                                                  const unsigned short* __restrict__ B,
                                                  const float* __restrict__ bias,
                                                  unsigned short* __restrict__ O0,
                                                  unsigned short* __restrict__ O1,
                                                  unsigned short* __restrict__ O2,
                                                  unsigned short* __restrict__ O3,
                                                  int M, int N, int K) {
    __shared__ char smem[131072];  // [buf][A 32KB | B 32KB]
    const int tid = threadIdx.x;
    const int wid = tid >> 6, lane = tid & 63;
    const int wm = wid >> 2, wn = wid & 3;
    const int lr = lane & 15, lkb = (lane >> 4) * 16;
    const int m0 = blockIdx.y * 256, n0 = blockIdx.x * 256;
    const int z = blockIdx.z;
    const int Kc = K / SPLITK, kb = z * Kc;
    const int NT = Kc / 64;

    f32x4 acc[8][4];
#pragma unroll
    for (int i = 0; i < 8; i++)
#pragma unroll
        for (int j = 0; j < 4; j++) acc[i][j] = (f32x4){0.f, 0.f, 0.f, 0.f};

    // hs: 0=A-h0 1=A-h1 2=B-h0 3=B-h1 ; dest linear, source pre-swizzled
    auto stage_half = [&](int c, int t, int hs) {
        const int op = hs >> 1, h = hs & 1;
        const unsigned short* G = op ? B : A;
        const int r0 = (op ? n0 : m0) + h * 128;
        char* base = smem + c * 65536 + op * 32768 + h * 16384;
        const int k0 = kb + t * 64;
#pragma unroll
        for (int q = 0; q < 2; q++) {
            int d = q * 8192 + wid * 1024 + lane * 16;
            int s = gswz(d);
            int row = s >> 7, colb = s & 127;
            gload_lds16(G + (size_t)(r0 + row) * K + k0 + (colb >> 1),
                        base + q * 8192 + wid * 1024);
        }
    };

    // prologue: tile 0 -> buf 0
    stage_half(0, 0, 0); stage_half(0, 0, 1); stage_half(0, 0, 2); stage_half(0, 0, 3);
    asm volatile("s_waitcnt vmcnt(0)" ::: "memory");
    __syncthreads();

    for (int t = 0; t < NT; ++t) {
        const int c = t & 1;
        const char* Ab = smem + c * 65536;
        const char* Bb = Ab + 32768;
        const bool pre = (t + 1 < NT);
        bf16x8 bfr[4][2];
#pragma unroll
        for (int p = 0; p < 4; ++p) {
            bf16x8 afr[2][2];
#pragma unroll
            for (int mi = 0; mi < 2; mi++)
#pragma unroll
                for (int ks = 0; ks < 2; ks++) {
                    int b = (wm * 128 + (p * 2 + mi) * 16 + lr) * 128 + ks * 64 + lkb;
                    afr[mi][ks] = *(const bf16x8*)(Ab + gswz(b));
                }
            if (p == 0) {
#pragma unroll
                for (int nb = 0; nb < 4; nb++)
#pragma unroll
                    for (int ks = 0; ks < 2; ks++) {
                        int b = (wn * 64 + nb * 16 + lr) * 128 + ks * 64 + lkb;
                        bfr[nb][ks] = *(const bf16x8*)(Bb + gswz(b));
                    }
            }
            if (pre) stage_half(c ^ 1, t + 1, p);
            __builtin_amdgcn_s_barrier();
            asm volatile("s_waitcnt lgkmcnt(0)" ::: "memory");
            __builtin_amdgcn_sched_barrier(0);
            __builtin_amdgcn_s_setprio(1);
#pragma unroll
            for (int mi = 0; mi < 2; mi++)
#pragma unroll
                for (int nb = 0; nb < 4; nb++)
#pragma unroll
                    for (int ks = 0; ks < 2; ks++)
                        acc[p * 2 + mi][nb] = __builtin_amdgcn_mfma_f32_16x16x32_bf16(
                            afr[mi][ks], bfr[nb][ks], acc[p * 2 + mi][nb], 0, 0, 0);
            __builtin_amdgcn_s_setprio(0);
            if (p == 3 && pre) asm volatile("s_waitcnt vmcnt(0)" ::: "memory");
            __builtin_amdgcn_s_barrier();
        }
    }

    // epilogue
    unsigned short* Op = (SPLITK == 1) ? O0 : (z == 0 ? O0 : z == 1 ? O1 : z == 2 ? O2 : O3);
    float bv[4];
#pragma unroll
    for (int nb = 0; nb < 4; nb++) bv[nb] = (z == 0) ? bias[n0 + wn * 64 + nb * 16 + lr] : 0.f;
    const int rr = (lane >> 4) * 4;
#pragma unroll
    for (int mb = 0; mb < 8; mb++)
#pragma unroll
        for (int nb = 0; nb < 4; nb++) {
            int col = n0 + wn * 64 + nb * 16 + lr;
#pragma unroll
            for (int r = 0; r < 4; r++) {
                int row = m0 + wm * 128 + mb * 16 + rr + r;
                float v = acc[mb][nb][r] + bv[nb];
                if (EPI == 2) v = fmaxf(v, 0.f);
                Op[(size_t)row * N + col] = f2bf(v);
            }
        }
}

// ---------------------------------------------------------------------------
// 128x128 dbuf GEMM (kept for Wo): C = A @ B^T + bias -> bf16
// ---------------------------------------------------------------------------
__global__ __launch_bounds__(256) void gemm_bt(const unsigned short* __restrict__ A,
                                               const unsigned short* __restrict__ B,
                                               const float* __restrict__ bias,
                                               unsigned short* __restrict__ Cout,
                                               int M, int N, int K) {
    __shared__ unsigned short Asm[2][128 * 32];
    __shared__ unsigned short Bsm[2][128 * 32];
    const int tid = threadIdx.x;
    const int wid = tid >> 6, lane = tid & 63;
    const int m0 = blockIdx.y * 128, n0 = blockIdx.x * 128;
    const int lr = lane & 15, lk = (lane >> 4) * 8;
    const int wr = (wid >> 1) * 64, wc = (wid & 1) * 64;
    const int nkt = K / 32;

    f32x4 acc[4][4];
#pragma unroll
    for (int i = 0; i < 4; i++)
#pragma unroll
        for (int j = 0; j < 4; j++) acc[i][j] = (f32x4){0.f, 0.f, 0.f, 0.f};

    const unsigned short* Ag = A + (size_t)m0 * K;
    const unsigned short* Bg = B + (size_t)n0 * K;

    auto stage = [&](int buf, int k0) {
#pragma unroll
        for (int p = 0; p < 2; ++p) {
            int idx = p * 4096 + wid * 1024 + lane * 16;
            int row = idx >> 6, ce = (idx & 63) >> 1;
            gload_lds16(Ag + (size_t)row * K + k0 + ce, (char*)Asm[buf] + p * 4096 + wid * 1024);
            gload_lds16(Bg + (size_t)row * K + k0 + ce, (char*)Bsm[buf] + p * 4096 + wid * 1024);
        }
    };

    stage(0, 0);
    for (int kt = 0; kt < nkt; ++kt) {
        const int cur = kt & 1;
        __syncthreads();
        if (kt + 1 < nkt) stage(cur ^ 1, (kt + 1) * 32);
        bf16x8 af[4], bfr[4];
#pragma unroll
        for (int m = 0; m < 4; m++) af[m] = *(const bf16x8*)&Asm[cur][(wr + m * 16 + lr) * 32 + lk];
#pragma unroll
        for (int n = 0; n < 4; n++) bfr[n] = *(const bf16x8*)&Bsm[cur][(wc + n * 16 + lr) * 32 + lk];
#pragma unroll
        for (int m = 0; m < 4; m++)
#pragma unroll
            for (int n = 0; n < 4; n++)
                acc[m][n] = __builtin_amdgcn_mfma_f32_16x16x32_bf16(af[m], bfr[n], acc[m][n], 0, 0, 0);
    }

    float bv[4];
#pragma unroll
    for (int n = 0; n < 4; n++) bv[n] = bias[n0 + wc + n * 16 + lr];
    const int r0 = (lane >> 4) * 4;
#pragma unroll
    for (int m = 0; m < 4; m++)
#pragma unroll
        for (int n = 0; n < 4; n++) {
            int col = n0 + wc + n * 16 + lr;
#pragma unroll
            for (int r = 0; r < 4; r++) {
                int row = m0 + wr + m * 16 + r0 + r;
                Cout[(size_t)row * N + col] = f2bf(acc[m][n][r] + bv[n]);
            }
        }
}

// ---------------------------------------------------------------------------
// V transpose: qkv V-part [b,s,h,d] -> vt [b,h,d,s]  (bf16)
// ---------------------------------------------------------------------------
__global__ __launch_bounds__(256) void vtrans(const unsigned short* __restrict__ qkv,
                                              unsigned short* __restrict__ vt) {
    __shared__ unsigned short T[64 * 64];
    const int tid = threadIdx.x;
    const int bh = blockIdx.y, b = bh >> 4, h = bh & 15;
    const int s0 = blockIdx.x * 64;
    const unsigned short* src = qkv + (size_t)(b * SS + s0) * 3072 + 2048 + h * 64;
#pragma unroll
    for (int p = 0; p < 2; p++) {
        int idx = p * 4096 + tid * 16;
        int row = idx >> 7, ce = (idx & 127) >> 1;
        ushort8v v = *(const ushort8v*)(src + (size_t)row * 3072 + ce);
        *(ushort8v*)((char*)T + swz(idx)) = v;
    }
    __syncthreads();
    unsigned short* dst = vt + (size_t)bh * 64 * SS + s0;
#pragma unroll
    for (int p = 0; p < 2; p++) {
        int idx = p * 4096 + tid * 16;
        int d = idx >> 7, t0 = (idx & 127) >> 1;
        ushort8v o;
#pragma unroll
        for (int i = 0; i < 8; i++)
            o[i] = *(const unsigned short*)((char*)T + swz((t0 + i) * 128 + d * 2));
        *(ushort8v*)(dst + (size_t)d * SS + t0) = o;
    }
}

// ---------------------------------------------------------------------------
// Flash attention. 1-D grid, XCD-grouped: all 16 q-tiles of a (b,h) map to
// one XCD so K/V tiles are L2-resident. log2-domain softmax (exp2), T13
// defer-max (THR=8). Swizzled K/V/P LDS, dbuf, single barrier per tile.
// ---------------------------------------------------------------------------
__global__ __launch_bounds__(256) void attn_fused(const unsigned short* __restrict__ qkv,
                                                  const unsigned short* __restrict__ vt,
                                                  const int* __restrict__ mask,
                                                  unsigned short* __restrict__ ctx) {
    __shared__ unsigned short Ksm[2][64 * 64];
    __shared__ unsigned short Vsm[2][64 * 64];
    __shared__ unsigned short Psm[4][16 * 64];
    __shared__ float maskadd[2][64];
    const int tid = threadIdx.x, wid = tid >> 6, lane = tid & 63;
    const int bid = blockIdx.x;
    const int xcd = bid & 7, loc = bid >> 3;
    const int bh = xcd * 8 + (loc >> 4), q0 = (loc & 15) * 64;
    const int b = bh >> 4, h = bh & 15;
    const int lr = lane & 15, lk2 = (lane >> 4) * 16;
    const size_t base = (size_t)b * SS * 3072 + h * 64;
    const float SC2 = 0.18033688011112042f;  // 0.125 * log2(e)

    bf16x8 qf[2];
    {
        const unsigned short* qp = qkv + base + (size_t)(q0 + wid * 16 + lr) * 3072;
        qf[0] = *(const bf16x8*)(qp + (lk2 >> 1));
        qf[1] = *(const bf16x8*)(qp + 32 + (lk2 >> 1));
    }
    float m_run[4] = {-3e38f, -3e38f, -3e38f, -3e38f};
    float l_run[4] = {0.f, 0.f, 0.f, 0.f};
    f32x4 oacc[4];
#pragma unroll
    for (int i = 0; i < 4; i++) oacc[i] = (f32x4){0.f, 0.f, 0.f, 0.f};

    const unsigned short* Kgb = qkv + base + 1024;
    const unsigned short* Vgb = vt + (size_t)bh * 64 * SS;

    auto stage = [&](int buf, int kt) {
#pragma unroll
        for (int p = 0; p < 2; p++) {
            int idx = p * 4096 + wid * 1024 + lane * 16;
            int s = swz(idx);
            int row = s >> 7, ce = (s & 127) >> 1;
            gload_lds16(Kgb + (size_t)(kt * 64 + row) * 3072 + ce,
                        (char*)Ksm[buf] + p * 4096 + wid * 1024);
            gload_lds16(Vgb + (size_t)row * SS + kt * 64 + ce,
                        (char*)Vsm[buf] + p * 4096 + wid * 1024);
        }
        if (tid < 64) maskadd[buf][tid] = mask[bh * SS + kt * 64 + tid] ? 0.f : -1.5e9f;
    };

    stage(0, 0);
    for (int kt = 0; kt < SS / 64; ++kt) {
        const int cur = kt & 1;
        __syncthreads();
        if (kt < SS / 64 - 1) stage(cur ^ 1, kt + 1);
        const char* Kb = (const char*)Ksm[cur];
        const char* Vb = (const char*)Vsm[cur];

        f32x4 sc[4];
#pragma unroll
        for (int nt = 0; nt < 4; nt++) {
            f32x4 a = (f32x4){0.f, 0.f, 0.f, 0.f};
            int rowb = (nt * 16 + lr) * 128;
            bf16x8 k0v = *(const bf16x8*)(Kb + swz(rowb + lk2));
            bf16x8 k1v = *(const bf16x8*)(Kb + swz(rowb + 64 + lk2));
            a = __builtin_amdgcn_mfma_f32_16x16x32_bf16(qf[0], k0v, a, 0, 0, 0);
            a = __builtin_amdgcn_mfma_f32_16x16x32_bf16(qf[1], k1v, a, 0, 0, 0);
            sc[nt] = a;
        }
        float mk[4];
#pragma unroll
        for (int nt = 0; nt < 4; nt++) mk[nt] = maskadd[cur][nt * 16 + lr];
        // scale to log2 domain + mask; per-row max
        float pmax[4];
#pragma unroll
        for (int r = 0; r < 4; r++) {
            float v = -3e38f;
#pragma unroll
            for (int nt = 0; nt < 4; nt++) {
                float s = sc[nt][r] * SC2 + mk[nt];
                sc[nt][r] = s;
                v = fmaxf(v, s);
            }
            v = fmaxf(v, __shfl_xor(v, 1));
            v = fmaxf(v, __shfl_xor(v, 2));
            v = fmaxf(v, __shfl_xor(v, 4));
            v = fmaxf(v, __shfl_xor(v, 8));
            pmax[r] = v;
        }
        bool okt = true;
#pragma unroll
        for (int r = 0; r < 4; r++) okt = okt && (pmax[r] <= m_run[r] + 8.f);
        const bool skip = __all(okt);
        if (!skip) {
#pragma unroll
            for (int r = 0; r < 4; r++) {
                float mnew = fmaxf(m_run[r], pmax[r]);
                float alpha = exp2f(m_run[r] - mnew);
                m_run[r] = mnew;
                l_run[r] *= alpha;
#pragma unroll
                for (int dt = 0; dt < 4; dt++) oacc[dt][r] *= alpha;
            }
        }
#pragma unroll
        for (int r = 0; r < 4; r++) {
            float ls = 0.f;
#pragma unroll
            for (int nt = 0; nt < 4; nt++) {
                float pexp = exp2f(sc[nt][r] - m_run[r]);
                sc[nt][r] = pexp;
                ls += pexp;
            }
            ls += __shfl_xor(ls, 1);
            ls += __shfl_xor(ls, 2);
            ls += __shfl_xor(ls, 4);
            ls += __shfl_xor(ls, 8);
            l_run[r] += ls;
        }
        const int prow = (lane >> 4) * 4;
        char* Pb = (char*)Psm[wid];
#pragma unroll
        for (int nt = 0; nt < 4; nt++)
#pragma unroll
            for (int r = 0; r < 4; r++)
                *(unsigned short*)(Pb + swz((prow + r) * 128 + (nt * 16 + lr) * 2)) = f2bf(sc[nt][r]);
        bf16x8 pf0 = *(const bf16x8*)(Pb + swz(lr * 128 + lk2));
        bf16x8 pf1 = *(const bf16x8*)(Pb + swz(lr * 128 + 64 + lk2));
#pragma unroll
        for (int dt = 0; dt < 4; dt++) {
            int rowb = (dt * 16 + lr) * 128;
            bf16x8 v0 = *(const bf16x8*)(Vb + swz(rowb + lk2));
            bf16x8 v1 = *(const bf16x8*)(Vb + swz(rowb + 64 + lk2));
            oacc[dt] = __builtin_amdgcn_mfma_f32_16x16x32_bf16(pf0, v0, oacc[dt], 0, 0, 0);
            oacc[dt] = __builtin_amdgcn_mfma_f32_16x16x32_bf16(pf1, v1, oacc[dt], 0, 0, 0);
        }
    }
#pragma unroll
    for (int dt = 0; dt < 4; dt++)
#pragma unroll
        for (int r = 0; r < 4; r++) {
            float v = oacc[dt][r] / l_run[r];
            int row = q0 + wid * 16 + (lane >> 4) * 4 + r;
            ctx[(size_t)(b * SS + row) * DDIM + h * 64 + dt * 16 + lr] = f2bf(v);
        }
}

// ---------------------------------------------------------------------------
// LN1: h = LN(bf2f(attno) + x) -> bf16
// ---------------------------------------------------------------------------
__global__ __launch_bounds__(256) void resid_ln1(const unsigned short* __restrict__ attno,
                                                 const float* __restrict__ x,
                                                 const float* __restrict__ gamma,
                                                 const float* __restrict__ beta,
                                                 unsigned short* __restrict__ hbf) {
    __shared__ float red[16];
    const int row = blockIdx.x, tid = threadIdx.x;
    const int wid = tid >> 6, lane = tid & 63;
    ushort4v av = ((const ushort4v*)(attno + (size_t)row * DDIM))[tid];
    float4 bv = ((const float4*)(x + (size_t)row * DDIM))[tid];
    float4 v;
    v.x = bf2f(av[0]) + bv.x; v.y = bf2f(av[1]) + bv.y;
    v.z = bf2f(av[2]) + bv.z; v.w = bf2f(av[3]) + bv.w;
    float s = v.x + v.y + v.z + v.w;
    float s2 = v.x * v.x + v.y * v.y + v.z * v.z + v.w * v.w;
#pragma unroll
    for (int off = 1; off < 64; off <<= 1) { s += __shfl_xor(s, off); s2 += __shfl_xor(s2, off); }
    if (lane == 0) { red[wid] = s; red[8 + wid] = s2; }
    __syncthreads();
    s = red[0] + red[1] + red[2] + red[3];
    s2 = red[8] + red[9] + red[10] + red[11];
    float mean = s * (1.f / 1024.f);
    float var = s2 * (1.f / 1024.f) - mean * mean;
    float rstd = rsqrtf(var + 1e-12f);
    float4 g = ((const float4*)gamma)[tid];
    float4 be = ((const float4*)beta)[tid];
    ushort4v u = {f2bf(g.x * (v.x - mean) * rstd + be.x),
                  f2bf(g.y * (v.y - mean) * rstd + be.y),
                  f2bf(g.z * (v.z - mean) * rstd + be.z),
                  f2bf(g.w * (v.w - mean) * rstd + be.w)};
    ((ushort4v*)(hbf + (size_t)row * DDIM))[tid] = u;
}

// ---------------------------------------------------------------------------
// LN2: out = LN(p0+p1+p2+p3 + h) -> f32 (fused split-K4 reduce)
// ---------------------------------------------------------------------------
__global__ __launch_bounds__(256) void resid_ln2(const unsigned short* __restrict__ p0,
                                                 const unsigned short* __restrict__ p1,
                                                 const unsigned short* __restrict__ p2,
                                                 const unsigned short* __restrict__ p3,
                                                 const unsigned short* __restrict__ hbf,
                                                 const float* __restrict__ gamma,
                                                 const float* __restrict__ beta,
                                                 float* __restrict__ out) {
    __shared__ float red[16];
    const int row = blockIdx.x, tid = threadIdx.x;
    const int wid = tid >> 6, lane = tid & 63;
    size_t off = (size_t)row * DDIM;
    ushort4v a0 = ((const ushort4v*)(p0 + off))[tid];
    ushort4v a1 = ((const ushort4v*)(p1 + off))[tid];
    ushort4v a2 = ((const ushort4v*)(p2 + off))[tid];
    ushort4v a3 = ((const ushort4v*)(p3 + off))[tid];
    ushort4v hv = ((const ushort4v*)(hbf + off))[tid];
    float4 v;
    v.x = bf2f(a0[0]) + bf2f(a1[0]) + bf2f(a2[0]) + bf2f(a3[0]) + bf2f(hv[0]);
    v.y = bf2f(a0[1]) + bf2f(a1[1]) + bf2f(a2[1]) + bf2f(a3[1]) + bf2f(hv[1]);
    v.z = bf2f(a0[2]) + bf2f(a1[2]) + bf2f(a2[2]) + bf2f(a3[2]) + bf2f(hv[2]);
    v.w = bf2f(a0[3]) + bf2f(a1[3]) + bf2f(a2[3]) + bf2f(a3[3]) + bf2f(hv[3]);
    float s = v.x + v.y + v.z + v.w;
    float s2 = v.x * v.x + v.y * v.y + v.z * v.z + v.w * v.w;
#pragma unroll
    for (int off2 = 1; off2 < 64; off2 <<= 1) { s += __shfl_xor(s, off2); s2 += __shfl_xor(s2, off2); }
    if (lane == 0) { red[wid] = s; red[8 + wid] = s2; }
    __syncthreads();
    s = red[0] + red[1] + red[2] + red[3];
    s2 = red[8] + red[9] + red[10] + red[11];
    float mean = s * (1.f / 1024.f);
    float var = s2 * (1.f / 1024.f) - mean * mean;
    float rstd = rsqrtf(var + 1e-12f);
    float4 g = ((const float4*)gamma)[tid];
    float4 be = ((const float4*)beta)[tid];
    float4 o;
    o.x = g.x * (v.x - mean) * rstd + be.x;
    o.y = g.y * (v.y - mean) * rstd + be.y;
    o.z = g.z * (v.z - mean) * rstd + be.z;
    o.w = g.w * (v.w - mean) * rstd + be.w;
    ((float4*)(out + off))[tid] = o;
}

// ---------------------------------------------------------------------------
extern "C" void kernel_launch(void* const* d_in, const int* in_sizes, int n_in,
                              void* d_out, int out_size, void* d_ws, size_t ws_size,
                              hipStream_t stream) {
    const float* x    = (const float*)d_in[0];
    const int*   mask = (const int*)d_in[1];
    const float* Wqkv = (const float*)d_in[2];
    const float* bqkv = (const float*)d_in[3];
    const float* Wo   = (const float*)d_in[4];
    const float* bo   = (const float*)d_in[5];
    const float* W1   = (const float*)d_in[6];
    const float* b1   = (const float*)d_in[7];
    const float* W2   = (const float*)d_in[8];
    const float* b2   = (const float*)d_in[9];
    const float* g1   = (const float*)d_in[10];
    const float* be1  = (const float*)d_in[11];
    const float* g2   = (const float*)d_in[12];
    const float* be2  = (const float*)d_in[13];
    float* out = (float*)d_out;

    // workspace (80 MB, lifetime-overlapped):
    // [0,8)   xbf -> vtb -> p0
    // [8,40)  qkvbf(8..32) + ctx(32..40) -> ff1 (written after both are dead... ctx dead after Wo)
    // [40,48) w1b -> p1          [48,56) w2b
    // [56,62) wqkvb + [62,64) wob -> p2 = [56,64)
    // [64,72) attno -> p3        [72,80) hbf
    char* ws = (char*)d_ws;
    unsigned short* xbf   = (unsigned short*)(ws + 0);
    unsigned short* vtb   = (unsigned short*)(ws + 0);
    unsigned short* p0    = (unsigned short*)(ws + 0);
    unsigned short* qkvbf = (unsigned short*)(ws + (8ull << 20));
    unsigned short* ff1   = (unsigned short*)(ws + (8ull << 20));
    unsigned short* ctx   = (unsigned short*)(ws + (32ull << 20));
    unsigned short* w1b   = (unsigned short*)(ws + (40ull << 20));
    unsigned short* p1    = (unsigned short*)(ws + (40ull << 20));
    unsigned short* w2b   = (unsigned short*)(ws + (48ull << 20));
    unsigned short* wqkvb = (unsigned short*)(ws + (56ull << 20));
    unsigned short* p2    = (unsigned short*)(ws + (56ull << 20));
    unsigned short* wob   = (unsigned short*)(ws + (62ull << 20));
    unsigned short* attno = (unsigned short*)(ws + (64ull << 20));
    unsigned short* p3    = (unsigned short*)(ws + (64ull << 20));
    unsigned short* hbf   = (unsigned short*)(ws + (72ull << 20));

    cvt_bf16<<<4096, 256, 0, stream>>>(x, xbf, 1048576);
    cvt_bf16<<<3072, 256, 0, stream>>>(Wqkv, wqkvb, 786432);
    cvt_bf16<<<1024, 256, 0, stream>>>(Wo, wob, 262144);
    cvt_bf16<<<4096, 256, 0, stream>>>(W1, w1b, 1048576);
    cvt_bf16<<<4096, 256, 0, stream>>>(W2, w2b, 1048576);

    // qkv = x @ Wqkv^T + bqkv -> bf16 [4096, 3072]
    gemm256<1, 1><<<dim3(12, 16, 1), 512, 0, stream>>>(xbf, wqkvb, bqkv,
        qkvbf, qkvbf, qkvbf, qkvbf, MTOK, 3072, 1024);
    vtrans<<<dim3(16, 64), 256, 0, stream>>>(qkvbf, vtb);
    attn_fused<<<1024, 256, 0, stream>>>(qkvbf, vtb, mask, ctx);
    // attn_out = ctx @ Wo^T + bo -> bf16
    gemm_bt<<<dim3(8, 32), 256, 0, stream>>>(ctx, wob, bo, attno, MTOK, 1024, 1024);
    // h = LN(attn_out + x) -> bf16
    resid_ln1<<<4096, 256, 0, stream>>>(attno, x, g1, be1, hbf);
    // ff1 = relu(h @ W1^T + b1) -> bf16 [4096, 4096]
    gemm256<2, 1><<<dim3(16, 16, 1), 512, 0, stream>>>(hbf, w1b, b1,
        ff1, ff1, ff1, ff1, MTOK, FFN_DIM, 1024);
    // ff2 partials (split-K x4) -> bf16
    gemm256<1, 4><<<dim3(4, 16, 4), 512, 0, stream>>>(ff1, w2b, b2,
        p0, p1, p2, p3, MTOK, DDIM, FFN_DIM);
    // out = LN(p0+p1+p2+p3 + h)
    resid_ln2<<<4096, 256, 0, stream>>>(p0, p1, p2, p3, hbf, g2, be2, out);
}

// Round 5
// 356.082 us; speedup vs baseline: 1.2855x; 1.0453x over previous
//
#include <hip/hip_runtime.h>

#define DDIM 1024
#define FFN_DIM 4096
#define SS 1024
#define MTOK 4096  // B*S

typedef __bf16 bf16x8 __attribute__((ext_vector_type(8)));
typedef float f32x4 __attribute__((ext_vector_type(4)));
typedef unsigned short ushort4v __attribute__((ext_vector_type(4)));
typedef unsigned short ushort8v __attribute__((ext_vector_type(8)));

__device__ __forceinline__ unsigned short f2bf(float f) {
    __bf16 h = (__bf16)f;  // single v_cvt (RNE); compiler packs pairs (m240)
    return __builtin_bit_cast(unsigned short, h);
}
__device__ __forceinline__ float bf2f(unsigned short u) {
    union { unsigned u; float f; } x;
    x.u = (unsigned)u << 16;
    return x.f;
}

// attention-tile swizzle (rows of 128B): involution on bits 4-6
__device__ __forceinline__ int swz(int off) {
    return off ^ ((((off >> 7) & 7) ^ ((off >> 10) & 1)) << 4);
}
// gemm256 tile swizzle: XOR 16B-slot (bits 4-6) by row bits 0-2 (bits 7-9).
__device__ __forceinline__ int gswz(int b) {
    return b ^ (((b >> 7) & 7) << 4);
}

// async global->LDS, 16B per lane. LDS dest = wave-uniform base + lane*16.
__device__ __forceinline__ void gload_lds16(const void* g, void* l) {
    __builtin_amdgcn_global_load_lds(
        (__attribute__((address_space(1))) unsigned int*)(unsigned long long)(g),
        (__attribute__((address_space(3))) unsigned int*)(l), 16, 0, 0);
}

// ---------------------------------------------------------------------------
// one fused f32->bf16 conversion pass over x, Wqkv, Wo, W1, W2 (4M float4s)
// ---------------------------------------------------------------------------
__global__ __launch_bounds__(256) void cvt_all(const float* __restrict__ x,
                                               const float* __restrict__ wqkv,
                                               const float* __restrict__ wo,
                                               const float* __restrict__ w1,
                                               const float* __restrict__ w2,
                                               unsigned short* __restrict__ xbf,
                                               unsigned short* __restrict__ wqkvb,
                                               unsigned short* __restrict__ wob,
                                               unsigned short* __restrict__ w1b,
                                               unsigned short* __restrict__ w2b) {
    int i = blockIdx.x * 256 + threadIdx.x;
    const float* src;
    unsigned short* dst;
    int off;
    if (i < 1048576)      { src = x;    dst = xbf;   off = i; }
    else if (i < 1835008) { src = wqkv; dst = wqkvb; off = i - 1048576; }
    else if (i < 2097152) { src = wo;   dst = wob;   off = i - 1835008; }
    else if (i < 3145728) { src = w1;   dst = w1b;   off = i - 2097152; }
    else                  { src = w2;   dst = w2b;   off = i - 3145728; }
    float4 v = ((const float4*)src)[off];
    ushort4v u = {f2bf(v.x), f2bf(v.y), f2bf(v.z), f2bf(v.w)};
    ((ushort4v*)dst)[off] = u;
}

// ---------------------------------------------------------------------------
// 256x256 8-wave 4-phase GEMM: C[M,N] = A[M,K] @ B[N,K]^T (+bias on z==0)
// bf16 in/out, f32 acc. EPI: 1 = bf16, 2 = relu->bf16.
// Schedule fix (T4): ALL 8 load-rounds of tile t+1 issue at phase 0 (buf c^1
// is read-complete by the barrier that opened tile t); single vmcnt(0) at end
// of phase 3, covered by phases 1-3 (~48 MFMA + 3 barriers). Never a
// just-issued-load drain.
// ---------------------------------------------------------------------------
template <int EPI, int SPLITK>
__global__ __launch_bounds__(512, 2) void gemm256(const unsigned short* __restrict__ A,
                                                  const unsigned short* __restrict__ B,
                                                  const float* __restrict__ bias,
                                                  unsigned short* __restrict__ O0,
                                                  unsigned short* __restrict__ O1,
                                                  unsigned short* __restrict__ O2,
                                                  unsigned short* __restrict__ O3,
                                                  int M, int N, int K) {
    __shared__ char smem[131072];  // [buf][A 32KB | B 32KB]
    const int tid = threadIdx.x;
    const int wid = tid >> 6, lane = tid & 63;
    const int wm = wid >> 2, wn = wid & 3;
    const int lr = lane & 15, lkb = (lane >> 4) * 16;
    const int m0 = blockIdx.y * 256, n0 = blockIdx.x * 256;
    const int z = blockIdx.z;
    const int Kc = K / SPLITK, kb = z * Kc;
    const int NT = Kc / 64;

    f32x4 acc[8][4];
#pragma unroll
    for (int i = 0; i < 8; i++)
#pragma unroll
        for (int j = 0; j < 4; j++) acc[i][j] = (f32x4){0.f, 0.f, 0.f, 0.f};

    // stage a full K-tile (A 32KB + B 32KB): dest linear, source pre-swizzled
    auto stage_tile = [&](int c, int t) {
        const int k0 = kb + t * 64;
#pragma unroll
        for (int hs = 0; hs < 4; ++hs) {
            const int op = hs >> 1, h = hs & 1;
            const unsigned short* G = op ? B : A;
            const int r0 = (op ? n0 : m0) + h * 128;
            char* base = smem + c * 65536 + op * 32768 + h * 16384;
#pragma unroll
            for (int q = 0; q < 2; q++) {
                int d = q * 8192 + wid * 1024 + lane * 16;
                int s = gswz(d);
                gload_lds16(G + (size_t)(r0 + (s >> 7)) * K + k0 + ((s & 127) >> 1),
                            base + q * 8192 + wid * 1024);
            }
        }
    };

    stage_tile(0, 0);
    asm volatile("s_waitcnt vmcnt(0)" ::: "memory");
    __syncthreads();

    for (int t = 0; t < NT; ++t) {
        const int c = t & 1;
        const char* Ab = smem + c * 65536;
        const char* Bb = Ab + 32768;
        const bool pre = (t + 1 < NT);
        bf16x8 bfr[4][2];
#pragma unroll
        for (int p = 0; p < 4; ++p) {
            bf16x8 afr[2][2];
#pragma unroll
            for (int mi = 0; mi < 2; mi++)
#pragma unroll
                for (int ks = 0; ks < 2; ks++) {
                    int b = (wm * 128 + (p * 2 + mi) * 16 + lr) * 128 + ks * 64 + lkb;
                    afr[mi][ks] = *(const bf16x8*)(Ab + gswz(b));
                }
            if (p == 0) {
#pragma unroll
                for (int nb = 0; nb < 4; nb++)
#pragma unroll
                    for (int ks = 0; ks < 2; ks++) {
                        int b = (wn * 64 + nb * 16 + lr) * 128 + ks * 64 + lkb;
                        bfr[nb][ks] = *(const bf16x8*)(Bb + gswz(b));
                    }
                if (pre) stage_tile(c ^ 1, t + 1);  // all 8 rounds, issued early
            }
            __builtin_amdgcn_s_barrier();
            asm volatile("s_waitcnt lgkmcnt(0)" ::: "memory");
            __builtin_amdgcn_sched_barrier(0);
            __builtin_amdgcn_s_setprio(1);
#pragma unroll
            for (int mi = 0; mi < 2; mi++)
#pragma unroll
                for (int nb = 0; nb < 4; nb++)
#pragma unroll
                    for (int ks = 0; ks < 2; ks++)
                        acc[p * 2 + mi][nb] = __builtin_amdgcn_mfma_f32_16x16x32_bf16(
                            afr[mi][ks], bfr[nb][ks], acc[p * 2 + mi][nb], 0, 0, 0);
            __builtin_amdgcn_s_setprio(0);
            if (p == 3 && pre) asm volatile("s_waitcnt vmcnt(0)" ::: "memory");
            __builtin_amdgcn_s_barrier();
        }
    }

    unsigned short* Op = (SPLITK == 1) ? O0 : (z == 0 ? O0 : z == 1 ? O1 : z == 2 ? O2 : O3);
    float bv[4];
#pragma unroll
    for (int nb = 0; nb < 4; nb++) bv[nb] = (z == 0) ? bias[n0 + wn * 64 + nb * 16 + lr] : 0.f;
    const int rr = (lane >> 4) * 4;
#pragma unroll
    for (int mb = 0; mb < 8; mb++)
#pragma unroll
        for (int nb = 0; nb < 4; nb++) {
            int col = n0 + wn * 64 + nb * 16 + lr;
#pragma unroll
            for (int r = 0; r < 4; r++) {
                int row = m0 + wm * 128 + mb * 16 + rr + r;
                float v = acc[mb][nb][r] + bv[nb];
                if (EPI == 2) v = fmaxf(v, 0.f);
                Op[(size_t)row * N + col] = f2bf(v);
            }
        }
}

// ---------------------------------------------------------------------------
// 128x128 dbuf GEMM (kept for Wo): C = A @ B^T + bias -> bf16
// ---------------------------------------------------------------------------
__global__ __launch_bounds__(256) void gemm_bt(const unsigned short* __restrict__ A,
                                               const unsigned short* __restrict__ B,
                                               const float* __restrict__ bias,
                                               unsigned short* __restrict__ Cout,
                                               int M, int N, int K) {
    __shared__ unsigned short Asm[2][128 * 32];
    __shared__ unsigned short Bsm[2][128 * 32];
    const int tid = threadIdx.x;
    const int wid = tid >> 6, lane = tid & 63;
    const int m0 = blockIdx.y * 128, n0 = blockIdx.x * 128;
    const int lr = lane & 15, lk = (lane >> 4) * 8;
    const int wr = (wid >> 1) * 64, wc = (wid & 1) * 64;
    const int nkt = K / 32;

    f32x4 acc[4][4];
#pragma unroll
    for (int i = 0; i < 4; i++)
#pragma unroll
        for (int j = 0; j < 4; j++) acc[i][j] = (f32x4){0.f, 0.f, 0.f, 0.f};

    const unsigned short* Ag = A + (size_t)m0 * K;
    const unsigned short* Bg = B + (size_t)n0 * K;

    auto stage = [&](int buf, int k0) {
#pragma unroll
        for (int p = 0; p < 2; ++p) {
            int idx = p * 4096 + wid * 1024 + lane * 16;
            int row = idx >> 6, ce = (idx & 63) >> 1;
            gload_lds16(Ag + (size_t)row * K + k0 + ce, (char*)Asm[buf] + p * 4096 + wid * 1024);
            gload_lds16(Bg + (size_t)row * K + k0 + ce, (char*)Bsm[buf] + p * 4096 + wid * 1024);
        }
    };

    stage(0, 0);
    for (int kt = 0; kt < nkt; ++kt) {
        const int cur = kt & 1;
        __syncthreads();
        if (kt + 1 < nkt) stage(cur ^ 1, (kt + 1) * 32);
        bf16x8 af[4], bfr[4];
#pragma unroll
        for (int m = 0; m < 4; m++) af[m] = *(const bf16x8*)&Asm[cur][(wr + m * 16 + lr) * 32 + lk];
#pragma unroll
        for (int n = 0; n < 4; n++) bfr[n] = *(const bf16x8*)&Bsm[cur][(wc + n * 16 + lr) * 32 + lk];
#pragma unroll
        for (int m = 0; m < 4; m++)
#pragma unroll
            for (int n = 0; n < 4; n++)
                acc[m][n] = __builtin_amdgcn_mfma_f32_16x16x32_bf16(af[m], bfr[n], acc[m][n], 0, 0, 0);
    }

    float bv[4];
#pragma unroll
    for (int n = 0; n < 4; n++) bv[n] = bias[n0 + wc + n * 16 + lr];
    const int r0 = (lane >> 4) * 4;
#pragma unroll
    for (int m = 0; m < 4; m++)
#pragma unroll
        for (int n = 0; n < 4; n++) {
            int col = n0 + wc + n * 16 + lr;
#pragma unroll
            for (int r = 0; r < 4; r++) {
                int row = m0 + wr + m * 16 + r0 + r;
                Cout[(size_t)row * N + col] = f2bf(acc[m][n][r] + bv[n]);
            }
        }
}

// ---------------------------------------------------------------------------
// V transpose: qkv V-part [b,s,h,d] -> vt [b,h,d,s]  (bf16)
// ---------------------------------------------------------------------------
__global__ __launch_bounds__(256) void vtrans(const unsigned short* __restrict__ qkv,
                                              unsigned short* __restrict__ vt) {
    __shared__ unsigned short T[64 * 64];
    const int tid = threadIdx.x;
    const int bh = blockIdx.y, b = bh >> 4, h = bh & 15;
    const int s0 = blockIdx.x * 64;
    const unsigned short* src = qkv + (size_t)(b * SS + s0) * 3072 + 2048 + h * 64;
#pragma unroll
    for (int p = 0; p < 2; p++) {
        int idx = p * 4096 + tid * 16;
        int row = idx >> 7, ce = (idx & 127) >> 1;
        ushort8v v = *(const ushort8v*)(src + (size_t)row * 3072 + ce);
        *(ushort8v*)((char*)T + swz(idx)) = v;
    }
    __syncthreads();
    unsigned short* dst = vt + (size_t)bh * 64 * SS + s0;
#pragma unroll
    for (int p = 0; p < 2; p++) {
        int idx = p * 4096 + tid * 16;
        int d = idx >> 7, t0 = (idx & 127) >> 1;
        ushort8v o;
#pragma unroll
        for (int i = 0; i < 8; i++)
            o[i] = *(const unsigned short*)((char*)T + swz((t0 + i) * 128 + d * 2));
        *(ushort8v*)(dst + (size_t)d * SS + t0) = o;
    }
}

// ---------------------------------------------------------------------------
// Flash attention. 1-D grid, XCD-grouped (L2-resident K/V). log2-domain
// softmax, defer-max (THR=8). Swizzled K/V/P LDS, dbuf, 1 barrier/tile.
// ---------------------------------------------------------------------------
__global__ __launch_bounds__(256) void attn_fused(const unsigned short* __restrict__ qkv,
                                                  const unsigned short* __restrict__ vt,
                                                  const int* __restrict__ mask,
                                                  unsigned short* __restrict__ ctx) {
    __shared__ unsigned short Ksm[2][64 * 64];
    __shared__ unsigned short Vsm[2][64 * 64];
    __shared__ unsigned short Psm[4][16 * 64];
    __shared__ float maskadd[2][64];
    const int tid = threadIdx.x, wid = tid >> 6, lane = tid & 63;
    const int bid = blockIdx.x;
    const int xcd = bid & 7, loc = bid >> 3;
    const int bh = xcd * 8 + (loc >> 4), q0 = (loc & 15) * 64;
    const int b = bh >> 4, h = bh & 15;
    const int lr = lane & 15, lk2 = (lane >> 4) * 16;
    const size_t base = (size_t)b * SS * 3072 + h * 64;
    const float SC2 = 0.18033688011112042f;  // 0.125 * log2(e)

    bf16x8 qf[2];
    {
        const unsigned short* qp = qkv + base + (size_t)(q0 + wid * 16 + lr) * 3072;
        qf[0] = *(const bf16x8*)(qp + (lk2 >> 1));
        qf[1] = *(const bf16x8*)(qp + 32 + (lk2 >> 1));
    }
    float m_run[4] = {-3e38f, -3e38f, -3e38f, -3e38f};
    float l_run[4] = {0.f, 0.f, 0.f, 0.f};
    f32x4 oacc[4];
#pragma unroll
    for (int i = 0; i < 4; i++) oacc[i] = (f32x4){0.f, 0.f, 0.f, 0.f};

    const unsigned short* Kgb = qkv + base + 1024;
    const unsigned short* Vgb = vt + (size_t)bh * 64 * SS;

    auto stage = [&](int buf, int kt) {
#pragma unroll
        for (int p = 0; p < 2; p++) {
            int idx = p * 4096 + wid * 1024 + lane * 16;
            int s = swz(idx);
            int row = s >> 7, ce = (s & 127) >> 1;
            gload_lds16(Kgb + (size_t)(kt * 64 + row) * 3072 + ce,
                        (char*)Ksm[buf] + p * 4096 + wid * 1024);
            gload_lds16(Vgb + (size_t)row * SS + kt * 64 + ce,
                        (char*)Vsm[buf] + p * 4096 + wid * 1024);
        }
        if (tid < 64) maskadd[buf][tid] = mask[bh * SS + kt * 64 + tid] ? 0.f : -1.5e9f;
    };

    stage(0, 0);
    for (int kt = 0; kt < SS / 64; ++kt) {
        const int cur = kt & 1;
        __syncthreads();
        if (kt < SS / 64 - 1) stage(cur ^ 1, kt + 1);
        const char* Kb = (const char*)Ksm[cur];
        const char* Vb = (const char*)Vsm[cur];

        f32x4 sc[4];
#pragma unroll
        for (int nt = 0; nt < 4; nt++) {
            f32x4 a = (f32x4){0.f, 0.f, 0.f, 0.f};
            int rowb = (nt * 16 + lr) * 128;
            bf16x8 k0v = *(const bf16x8*)(Kb + swz(rowb + lk2));
            bf16x8 k1v = *(const bf16x8*)(Kb + swz(rowb + 64 + lk2));
            a = __builtin_amdgcn_mfma_f32_16x16x32_bf16(qf[0], k0v, a, 0, 0, 0);
            a = __builtin_amdgcn_mfma_f32_16x16x32_bf16(qf[1], k1v, a, 0, 0, 0);
            sc[nt] = a;
        }
        float mk[4];
#pragma unroll
        for (int nt = 0; nt < 4; nt++) mk[nt] = maskadd[cur][nt * 16 + lr];
        float pmax[4];
#pragma unroll
        for (int r = 0; r < 4; r++) {
            float v = -3e38f;
#pragma unroll
            for (int nt = 0; nt < 4; nt++) {
                float s = sc[nt][r] * SC2 + mk[nt];
                sc[nt][r] = s;
                v = fmaxf(v, s);
            }
            v = fmaxf(v, __shfl_xor(v, 1));
            v = fmaxf(v, __shfl_xor(v, 2));
            v = fmaxf(v, __shfl_xor(v, 4));
            v = fmaxf(v, __shfl_xor(v, 8));
            pmax[r] = v;
        }
        bool okt = true;
#pragma unroll
        for (int r = 0; r < 4; r++) okt = okt && (pmax[r] <= m_run[r] + 8.f);
        const bool skip = __all(okt);
        if (!skip) {
#pragma unroll
            for (int r = 0; r < 4; r++) {
                float mnew = fmaxf(m_run[r], pmax[r]);
                float alpha = exp2f(m_run[r] - mnew);
                m_run[r] = mnew;
                l_run[r] *= alpha;
#pragma unroll
                for (int dt = 0; dt < 4; dt++) oacc[dt][r] *= alpha;
            }
        }
#pragma unroll
        for (int r = 0; r < 4; r++) {
            float ls = 0.f;
#pragma unroll
            for (int nt = 0; nt < 4; nt++) {
                float pexp = exp2f(sc[nt][r] - m_run[r]);
                sc[nt][r] = pexp;
                ls += pexp;
            }
            ls += __shfl_xor(ls, 1);
            ls += __shfl_xor(ls, 2);
            ls += __shfl_xor(ls, 4);
            ls += __shfl_xor(ls, 8);
            l_run[r] += ls;
        }
        const int prow = (lane >> 4) * 4;
        char* Pb = (char*)Psm[wid];
#pragma unroll
        for (int nt = 0; nt < 4; nt++)
#pragma unroll
            for (int r = 0; r < 4; r++)
                *(unsigned short*)(Pb + swz((prow + r) * 128 + (nt * 16 + lr) * 2)) = f2bf(sc[nt][r]);
        bf16x8 pf0 = *(const bf16x8*)(Pb + swz(lr * 128 + lk2));
        bf16x8 pf1 = *(const bf16x8*)(Pb + swz(lr * 128 + 64 + lk2));
#pragma unroll
        for (int dt = 0; dt < 4; dt++) {
            int rowb = (dt * 16 + lr) * 128;
            bf16x8 v0 = *(const bf16x8*)(Vb + swz(rowb + lk2));
            bf16x8 v1 = *(const bf16x8*)(Vb + swz(rowb + 64 + lk2));
            oacc[dt] = __builtin_amdgcn_mfma_f32_16x16x32_bf16(pf0, v0, oacc[dt], 0, 0, 0);
            oacc[dt] = __builtin_amdgcn_mfma_f32_16x16x32_bf16(pf1, v1, oacc[dt], 0, 0, 0);
        }
    }
#pragma unroll
    for (int dt = 0; dt < 4; dt++)
#pragma unroll
        for (int r = 0; r < 4; r++) {
            float v = oacc[dt][r] / l_run[r];
            int row = q0 + wid * 16 + (lane >> 4) * 4 + r;
            ctx[(size_t)(b * SS + row) * DDIM + h * 64 + dt * 16 + lr] = f2bf(v);
        }
}

// ---------------------------------------------------------------------------
// LN1: h = LN(bf2f(attno) + x) -> bf16
// ---------------------------------------------------------------------------
__global__ __launch_bounds__(256) void resid_ln1(const unsigned short* __restrict__ attno,
                                                 const float* __restrict__ x,
                                                 const float* __restrict__ gamma,
                                                 const float* __restrict__ beta,
                                                 unsigned short* __restrict__ hbf) {
    __shared__ float red[16];
    const int row = blockIdx.x, tid = threadIdx.x;
    const int wid = tid >> 6, lane = tid & 63;
    ushort4v av = ((const ushort4v*)(attno + (size_t)row * DDIM))[tid];
    float4 bv = ((const float4*)(x + (size_t)row * DDIM))[tid];
    float4 v;
    v.x = bf2f(av[0]) + bv.x; v.y = bf2f(av[1]) + bv.y;
    v.z = bf2f(av[2]) + bv.z; v.w = bf2f(av[3]) + bv.w;
    float s = v.x + v.y + v.z + v.w;
    float s2 = v.x * v.x + v.y * v.y + v.z * v.z + v.w * v.w;
#pragma unroll
    for (int off = 1; off < 64; off <<= 1) { s += __shfl_xor(s, off); s2 += __shfl_xor(s2, off); }
    if (lane == 0) { red[wid] = s; red[8 + wid] = s2; }
    __syncthreads();
    s = red[0] + red[1] + red[2] + red[3];
    s2 = red[8] + red[9] + red[10] + red[11];
    float mean = s * (1.f / 1024.f);
    float var = s2 * (1.f / 1024.f) - mean * mean;
    float rstd = rsqrtf(var + 1e-12f);
    float4 g = ((const float4*)gamma)[tid];
    float4 be = ((const float4*)beta)[tid];
    ushort4v u = {f2bf(g.x * (v.x - mean) * rstd + be.x),
                  f2bf(g.y * (v.y - mean) * rstd + be.y),
                  f2bf(g.z * (v.z - mean) * rstd + be.z),
                  f2bf(g.w * (v.w - mean) * rstd + be.w)};
    ((ushort4v*)(hbf + (size_t)row * DDIM))[tid] = u;
}

// ---------------------------------------------------------------------------
// LN2: out = LN(p0+p1+p2+p3 + h) -> f32 (fused split-K4 reduce)
// ---------------------------------------------------------------------------
__global__ __launch_bounds__(256) void resid_ln2(const unsigned short* __restrict__ p0,
                                                 const unsigned short* __restrict__ p1,
                                                 const unsigned short* __restrict__ p2,
                                                 const unsigned short* __restrict__ p3,
                                                 const unsigned short* __restrict__ hbf,
                                                 const float* __restrict__ gamma,
                                                 const float* __restrict__ beta,
                                                 float* __restrict__ out) {
    __shared__ float red[16];
    const int row = blockIdx.x, tid = threadIdx.x;
    const int wid = tid >> 6, lane = tid & 63;
    size_t off = (size_t)row * DDIM;
    ushort4v a0 = ((const ushort4v*)(p0 + off))[tid];
    ushort4v a1 = ((const ushort4v*)(p1 + off))[tid];
    ushort4v a2 = ((const ushort4v*)(p2 + off))[tid];
    ushort4v a3 = ((const ushort4v*)(p3 + off))[tid];
    ushort4v hv = ((const ushort4v*)(hbf + off))[tid];
    float4 v;
    v.x = bf2f(a0[0]) + bf2f(a1[0]) + bf2f(a2[0]) + bf2f(a3[0]) + bf2f(hv[0]);
    v.y = bf2f(a0[1]) + bf2f(a1[1]) + bf2f(a2[1]) + bf2f(a3[1]) + bf2f(hv[1]);
    v.z = bf2f(a0[2]) + bf2f(a1[2]) + bf2f(a2[2]) + bf2f(a3[2]) + bf2f(hv[2]);
    v.w = bf2f(a0[3]) + bf2f(a1[3]) + bf2f(a2[3]) + bf2f(a3[3]) + bf2f(hv[3]);
    float s = v.x + v.y + v.z + v.w;
    float s2 = v.x * v.x + v.y * v.y + v.z * v.z + v.w * v.w;
#pragma unroll
    for (int off2 = 1; off2 < 64; off2 <<= 1) { s += __shfl_xor(s, off2); s2 += __shfl_xor(s2, off2); }
    if (lane == 0) { red[wid] = s; red[8 + wid] = s2; }
    __syncthreads();
    s = red[0] + red[1] + red[2] + red[3];
    s2 = red[8] + red[9] + red[10] + red[11];
    float mean = s * (1.f / 1024.f);
    float var = s2 * (1.f / 1024.f) - mean * mean;
    float rstd = rsqrtf(var + 1e-12f);
    float4 g = ((const float4*)gamma)[tid];
    float4 be = ((const float4*)beta)[tid];
    float4 o;
    o.x = g.x * (v.x - mean) * rstd + be.x;
    o.y = g.y * (v.y - mean) * rstd + be.y;
    o.z = g.z * (v.z - mean) * rstd + be.z;
    o.w = g.w * (v.w - mean) * rstd + be.w;
    ((float4*)(out + off))[tid] = o;
}

// ---------------------------------------------------------------------------
extern "C" void kernel_launch(void* const* d_in, const int* in_sizes, int n_in,
                              void* d_out, int out_size, void* d_ws, size_t ws_size,
                              hipStream_t stream) {
    const float* x    = (const float*)d_in[0];
    const int*   mask = (const int*)d_in[1];
    const float* Wqkv = (const float*)d_in[2];
    const float* bqkv = (const float*)d_in[3];
    const float* Wo   = (const float*)d_in[4];
    const float* bo   = (const float*)d_in[5];
    const float* W1   = (const float*)d_in[6];
    const float* b1   = (const float*)d_in[7];
    const float* W2   = (const float*)d_in[8];
    const float* b2   = (const float*)d_in[9];
    const float* g1   = (const float*)d_in[10];
    const float* be1  = (const float*)d_in[11];
    const float* g2   = (const float*)d_in[12];
    const float* be2  = (const float*)d_in[13];
    float* out = (float*)d_out;

    // workspace (80 MB, lifetime-overlapped):
    // [0,8)   xbf -> vtb -> p0
    // [8,40)  qkvbf(8..32) + ctx(32..40) -> ff1
    // [40,48) w1b -> p1          [48,56) w2b
    // [56,62) wqkvb + [62,64) wob -> p2 = [56,64)
    // [64,72) attno -> p3        [72,80) hbf
    char* ws = (char*)d_ws;
    unsigned short* xbf   = (unsigned short*)(ws + 0);
    unsigned short* vtb   = (unsigned short*)(ws + 0);
    unsigned short* p0    = (unsigned short*)(ws + 0);
    unsigned short* qkvbf = (unsigned short*)(ws + (8ull << 20));
    unsigned short* ff1   = (unsigned short*)(ws + (8ull << 20));
    unsigned short* ctx   = (unsigned short*)(ws + (32ull << 20));
    unsigned short* w1b   = (unsigned short*)(ws + (40ull << 20));
    unsigned short* p1    = (unsigned short*)(ws + (40ull << 20));
    unsigned short* w2b   = (unsigned short*)(ws + (48ull << 20));
    unsigned short* wqkvb = (unsigned short*)(ws + (56ull << 20));
    unsigned short* p2    = (unsigned short*)(ws + (56ull << 20));
    unsigned short* wob   = (unsigned short*)(ws + (62ull << 20));
    unsigned short* attno = (unsigned short*)(ws + (64ull << 20));
    unsigned short* p3    = (unsigned short*)(ws + (64ull << 20));
    unsigned short* hbf   = (unsigned short*)(ws + (72ull << 20));

    cvt_all<<<16384, 256, 0, stream>>>(x, Wqkv, Wo, W1, W2, xbf, wqkvb, wob, w1b, w2b);

    // qkv = x @ Wqkv^T + bqkv -> bf16 [4096, 3072]
    gemm256<1, 1><<<dim3(12, 16, 1), 512, 0, stream>>>(xbf, wqkvb, bqkv,
        qkvbf, qkvbf, qkvbf, qkvbf, MTOK, 3072, 1024);
    vtrans<<<dim3(16, 64), 256, 0, stream>>>(qkvbf, vtb);
    attn_fused<<<1024, 256, 0, stream>>>(qkvbf, vtb, mask, ctx);
    // attn_out = ctx @ Wo^T + bo -> bf16
    gemm_bt<<<dim3(8, 32), 256, 0, stream>>>(ctx, wob, bo, attno, MTOK, 1024, 1024);
    // h = LN(attn_out + x) -> bf16
    resid_ln1<<<4096, 256, 0, stream>>>(attno, x, g1, be1, hbf);
    // ff1 = relu(h @ W1^T + b1) -> bf16 [4096, 4096]
    gemm256<2, 1><<<dim3(16, 16, 1), 512, 0, stream>>>(hbf, w1b, b1,
        ff1, ff1, ff1, ff1, MTOK, FFN_DIM, 1024);
    // ff2 partials (split-K x4) -> bf16
    gemm256<1, 4><<<dim3(4, 16, 4), 512, 0, stream>>>(ff1, w2b, b2,
        p0, p1, p2, p3, MTOK, DDIM, FFN_DIM);
    // out = LN(p0+p1+p2+p3 + h)
    resid_ln2<<<4096, 256, 0, stream>>>(p0, p1, p2, p3, hbf, g2, be2, out);
}